// Round 1
// baseline (948.468 us; speedup 1.0000x reference)
//
#include <hip/hip_runtime.h>
#include <stdint.h>

typedef unsigned short u16;
typedef __bf16 bf16x8 __attribute__((ext_vector_type(8)));
typedef float f32x4 __attribute__((ext_vector_type(4)));

#define D_MODEL 4096
#define T_SEQ   2048
#define B_SZ    2
#define NH      32
#define NKV     8
#define HDIM    128
#define WINDOW  1024
#define NGLOB   32

static constexpr float SCALE = 0.08838834764831845f; // 1/sqrt(128)

__device__ __forceinline__ u16 f2b(float f) {
  __bf16 h = (__bf16)f;
  return __builtin_bit_cast(u16, h);
}
__device__ __forceinline__ float b2f(u16 u) {
  return (float)__builtin_bit_cast(__bf16, u);
}

// ---------------- x f32 -> bf16 (vectorized) ----------------
__global__ __launch_bounds__(256) void convert_bf16_kernel(const float* __restrict__ in,
                                                           u16* __restrict__ outp, int n4) {
  int i = blockIdx.x * 256 + threadIdx.x;
  if (i >= n4) return;
  float4 v = ((const float4*)in)[i];
  ushort4 o;
  o.x = f2b(v.x); o.y = f2b(v.y); o.z = f2b(v.z); o.w = f2b(v.w);
  ((ushort4*)outp)[i] = o;
}

// ---------------- W [K,N] f32 -> Wt [N,K] bf16 ----------------
__global__ __launch_bounds__(256) void transpose_w_kernel(const float* __restrict__ W,
                                                          u16* __restrict__ Wt, int Kd, int Nd) {
  __shared__ float tile[32][33];
  int tx = threadIdx.x & 31, ty = threadIdx.x >> 5;
  int bx = blockIdx.x * 32; // N
  int by = blockIdx.y * 32; // K
#pragma unroll
  for (int i = 0; i < 4; ++i)
    tile[ty + i * 8][tx] = W[(size_t)(by + ty + i * 8) * Nd + bx + tx];
  __syncthreads();
#pragma unroll
  for (int i = 0; i < 4; ++i)
    Wt[(size_t)(bx + ty + i * 8) * Kd + by + tx] = f2b(tile[tx][ty + i * 8]);
}

// ---------------- bf16 GEMM: C[M,N] = A[M,K] @ Bt[N,K]^T ----------------
// 128x128 tile, 4 waves (2x2), 4x4 16x16x32 frags/wave, global_load_lds width 16.
template <typename CT>
__global__ __launch_bounds__(256) void gemm_bt_kernel(const u16* __restrict__ A,
                                                      const u16* __restrict__ Bt,
                                                      CT* __restrict__ C, int N, int K) {
  __shared__ u16 As[128 * 32];
  __shared__ u16 Bs[128 * 32];
  int tid = threadIdx.x;
  int wave = tid >> 6, lane = tid & 63;
  int g = lane >> 4, li = lane & 15;
  int m0 = blockIdx.y * 128, n0 = blockIdx.x * 128;
  int wr = wave >> 1, wc = wave & 1;
  f32x4 zz = {0.f, 0.f, 0.f, 0.f};
  f32x4 acc[4][4];
#pragma unroll
  for (int m = 0; m < 4; ++m)
#pragma unroll
    for (int n = 0; n < 4; ++n) acc[m][n] = zz;

  for (int k0 = 0; k0 < K; k0 += 32) {
    __syncthreads(); // prior iter's LDS reads must drain before overwrite
#pragma unroll
    for (int i = 0; i < 2; ++i) {
      int instr = wave * 2 + i;
      int o = instr * 512 + lane * 8; // element offset within 128x32 tile
      int r = o >> 5, c = o & 31;
      const u16* gA = A + (size_t)(m0 + r) * K + k0 + c;
      const u16* gB = Bt + (size_t)(n0 + r) * K + k0 + c;
      __builtin_amdgcn_global_load_lds((__attribute__((address_space(1))) void*)gA,
                                       (__attribute__((address_space(3))) void*)(As + instr * 512),
                                       16, 0, 0);
      __builtin_amdgcn_global_load_lds((__attribute__((address_space(1))) void*)gB,
                                       (__attribute__((address_space(3))) void*)(Bs + instr * 512),
                                       16, 0, 0);
    }
    __syncthreads(); // compiler drains vmcnt(0) here
    bf16x8 af[4], bf[4];
#pragma unroll
    for (int m = 0; m < 4; ++m)
      af[m] = *(const bf16x8*)&As[(wr * 64 + m * 16 + li) * 32 + g * 8];
#pragma unroll
    for (int n = 0; n < 4; ++n)
      bf[n] = *(const bf16x8*)&Bs[(wc * 64 + n * 16 + li) * 32 + g * 8];
#pragma unroll
    for (int m = 0; m < 4; ++m)
#pragma unroll
      for (int n = 0; n < 4; ++n)
        acc[m][n] = __builtin_amdgcn_mfma_f32_16x16x32_bf16(af[m], bf[n], acc[m][n], 0, 0, 0);
  }
  // epilogue: C/D layout col=lane&15, row=(lane>>4)*4+reg (m89-verified)
#pragma unroll
  for (int m = 0; m < 4; ++m)
#pragma unroll
    for (int n = 0; n < 4; ++n)
#pragma unroll
      for (int r = 0; r < 4; ++r) {
        int row = m0 + wr * 64 + m * 16 + g * 4 + r;
        int col = n0 + wc * 64 + n * 16 + li;
        if constexpr (sizeof(CT) == 2)
          C[(size_t)row * N + col] = (CT)f2b(acc[m][n][r]);
        else
          C[(size_t)row * N + col] = acc[m][n][r];
      }
}

// ---------------- RoPE in place on bf16 q,k ----------------
__global__ __launch_bounds__(256) void rope_kernel(u16* __restrict__ qb, u16* __restrict__ kb,
                                                   const float* __restrict__ cosp,
                                                   const float* __restrict__ sinp) {
  int idx = blockIdx.x * 256 + threadIdx.x; // total B*T*(NH+NKV)*64
  int d = idx & 63;
  int rest = idx >> 6;
  int hh = rest % (NH + NKV);
  int bt = rest / (NH + NKV);
  if (bt >= B_SZ * T_SEQ) return;
  int tok = bt & (T_SEQ - 1);
  float c = cosp[tok * HDIM + d], s = sinp[tok * HDIM + d]; // table duplicated at d+64
  u16* base = (hh < NH) ? (qb + (size_t)bt * (NH * HDIM) + hh * HDIM)
                        : (kb + (size_t)bt * (NKV * HDIM) + (hh - NH) * HDIM);
  float x1 = b2f(base[d]), x2 = b2f(base[d + 64]);
  base[d] = f2b(x1 * c - x2 * s);
  base[d + 64] = f2b(x2 * c + x1 * s);
}

// ---------------- flash attention, QB=64 (4 waves x 16 rows), KB=32 ----------------
__global__ __launch_bounds__(256) void attn_kernel(const u16* __restrict__ qp,
                                                   const u16* __restrict__ kp,
                                                   const u16* __restrict__ vp,
                                                   u16* __restrict__ ctx) {
  __shared__ u16 Kt[32 * 128]; // XOR-swizzled rows
  __shared__ u16 Vt[32 * 128];
  __shared__ u16 Pl[4][16 * 32]; // per-wave P bounce
  int tid = threadIdx.x;
  int w = tid >> 6, lane = tid & 63;
  int g = lane >> 4, li = lane & 15;
  int i0 = blockIdx.x * 64;
  int h = blockIdx.y, b = blockIdx.z;
  int kh = h >> 2; // repeat_interleave: q-head h -> kv-head h/4
  f32x4 zz = {0.f, 0.f, 0.f, 0.f};

  // Q fragments in registers (A-frag: row=li, k=g*8+e within 32-chunk c)
  bf16x8 qf[4];
  size_t qrow = (size_t)(b * T_SEQ + i0 + w * 16 + li) * (NH * HDIM) + h * HDIM;
#pragma unroll
  for (int c = 0; c < 4; ++c) qf[c] = *(const bf16x8*)(qp + qrow + c * 32 + g * 8);

  f32x4 o[8];
#pragma unroll
  for (int f = 0; f < 8; ++f) o[f] = zz;
  float m_s[4] = {-1e30f, -1e30f, -1e30f, -1e30f};
  float l_s[4] = {0.f, 0.f, 0.f, 0.f};

  int jmax = i0 + 63;
  for (int j0 = 0; j0 <= jmax; j0 += 32) {
    if (!((j0 < NGLOB) || (j0 + 31 > i0 - WINDOW))) continue; // fully-masked tile
    __syncthreads();
    // stage K,V tiles [32][128] bf16, byte-swizzle ^((row&7)<<4)
#pragma unroll
    for (int i = 0; i < 2; ++i) {
      int o8 = tid + 256 * i;
      int row = o8 >> 4, ch = o8 & 15;
      size_t gsrc = (size_t)(b * T_SEQ + j0 + row) * (NKV * HDIM) + kh * HDIM + ch * 8;
      int idx = (row * 128 + ch * 8) ^ ((row & 7) << 3);
      *(bf16x8*)&Kt[idx] = *(const bf16x8*)(kp + gsrc);
      *(bf16x8*)&Vt[idx] = *(const bf16x8*)(vp + gsrc);
    }
    __syncthreads();

    // S = Q @ K^T, two 16-key blocks
    f32x4 s0 = zz, s1 = zz;
#pragma unroll
    for (int c = 0; c < 4; ++c) {
      int hd0 = c * 32 + g * 8;
      int key0 = li;
      bf16x8 kf0 = *(const bf16x8*)&Kt[(key0 * 128 + hd0) ^ ((key0 & 7) << 3)];
      s0 = __builtin_amdgcn_mfma_f32_16x16x32_bf16(qf[c], kf0, s0, 0, 0, 0);
      int key1 = 16 + li;
      bf16x8 kf1 = *(const bf16x8*)&Kt[(key1 * 128 + hd0) ^ ((key1 & 7) << 3)];
      s1 = __builtin_amdgcn_mfma_f32_16x16x32_bf16(qf[c], kf1, s1, 0, 0, 0);
    }

    // mask + online softmax (rows 4g+r, cols li / 16+li)
    float p0[4], p1[4], corr[4];
#pragma unroll
    for (int r = 0; r < 4; ++r) {
      int irow = i0 + w * 16 + g * 4 + r;
      int ja = j0 + li, jb = j0 + 16 + li;
      float x0 = s0[r] * SCALE;
      float x1v = s1[r] * SCALE;
      bool v0 = (ja <= irow) && ((ja > irow - WINDOW) || (ja < NGLOB));
      bool v1 = (jb <= irow) && ((jb > irow - WINDOW) || (jb < NGLOB));
      x0 = v0 ? x0 : -1e30f;
      x1v = v1 ? x1v : -1e30f;
      float mt = fmaxf(x0, x1v);
#pragma unroll
      for (int dd = 1; dd < 16; dd <<= 1) mt = fmaxf(mt, __shfl_xor(mt, dd, 64));
      float mn = fmaxf(m_s[r], mt);
      corr[r] = __expf(m_s[r] - mn);
      m_s[r] = mn;
      p0[r] = __expf(x0 - mn);
      p1[r] = __expf(x1v - mn);
      float rs = p0[r] + p1[r];
#pragma unroll
      for (int dd = 1; dd < 16; dd <<= 1) rs += __shfl_xor(rs, dd, 64);
      l_s[r] = l_s[r] * corr[r] + rs;
    }
#pragma unroll
    for (int f = 0; f < 8; ++f) {
      o[f][0] *= corr[0]; o[f][1] *= corr[1];
      o[f][2] *= corr[2]; o[f][3] *= corr[3];
    }

    // P (C-layout) -> per-wave LDS -> A-frag layout
#pragma unroll
    for (int r = 0; r < 4; ++r) {
      Pl[w][(g * 4 + r) * 32 + li] = f2b(p0[r]);
      Pl[w][(g * 4 + r) * 32 + 16 + li] = f2b(p1[r]);
    }
    bf16x8 pa = *(const bf16x8*)&Pl[w][li * 32 + g * 8];

    // O += P @ V  (V B-frag gathered as scalar u16: V[8g+e][16f+li])
#pragma unroll
    for (int f = 0; f < 8; ++f) {
      uint32_t vv[4];
#pragma unroll
      for (int e2 = 0; e2 < 4; ++e2) {
        int k0v = g * 8 + e2 * 2;
        int hd = f * 16 + li;
        uint32_t lo = Vt[(k0v * 128 + hd) ^ ((k0v & 7) << 3)];
        uint32_t hi = Vt[((k0v + 1) * 128 + hd) ^ (((k0v + 1) & 7) << 3)];
        vv[e2] = lo | (hi << 16);
      }
      uint4 uv = {vv[0], vv[1], vv[2], vv[3]};
      bf16x8 vf = __builtin_bit_cast(bf16x8, uv);
      o[f] = __builtin_amdgcn_mfma_f32_16x16x32_bf16(pa, vf, o[f], 0, 0, 0);
    }
  }

  // epilogue: ctx[b*T+i][h*128+hd] bf16
#pragma unroll
  for (int f = 0; f < 8; ++f)
#pragma unroll
    for (int r = 0; r < 4; ++r) {
      size_t orow = (size_t)(b * T_SEQ + i0 + w * 16 + g * 4 + r) * (NH * HDIM) + h * HDIM + f * 16 + li;
      ctx[orow] = f2b(o[f][r] / l_s[r]);
    }
}

extern "C" void kernel_launch(void* const* d_in, const int* in_sizes, int n_in,
                              void* d_out, int out_size, void* d_ws, size_t ws_size,
                              hipStream_t stream) {
  const float* x    = (const float*)d_in[0];
  const float* Wq   = (const float*)d_in[1];
  const float* Wk   = (const float*)d_in[2];
  const float* Wv   = (const float*)d_in[3];
  const float* Wo   = (const float*)d_in[4];
  const float* cosp = (const float*)d_in[5];
  const float* sinp = (const float*)d_in[6];
  // d_in[7] = mask: recomputed analytically in-kernel.

  char* ws = (char*)d_ws;
  // ws layout (bytes); ctx aliases xb (xb dead after QKV GEMMs, stream-ordered)
  u16* xb  = (u16*)(ws + 0ull);          // 32 MiB  [4096,4096] bf16
  u16* Wqt = (u16*)(ws + 33554432ull);   // 32 MiB  [4096,4096]
  u16* Wkt = (u16*)(ws + 67108864ull);   // 8 MiB   [1024,4096]
  u16* Wvt = (u16*)(ws + 75497472ull);   // 8 MiB
  u16* Wot = (u16*)(ws + 83886080ull);   // 32 MiB
  u16* qb  = (u16*)(ws + 117440512ull);  // 32 MiB  [B*T, H*HD]
  u16* kb  = (u16*)(ws + 150994944ull);  // 8 MiB   [B*T, KH*HD]
  u16* vb  = (u16*)(ws + 159383552ull);  // 8 MiB   -> total 160 MiB
  u16* ctx = xb;

  convert_bf16_kernel<<<16384, 256, 0, stream>>>(x, xb, 4194304);
  transpose_w_kernel<<<dim3(128, 128), 256, 0, stream>>>(Wq, Wqt, 4096, 4096);
  transpose_w_kernel<<<dim3(32, 128), 256, 0, stream>>>(Wk, Wkt, 4096, 1024);
  transpose_w_kernel<<<dim3(32, 128), 256, 0, stream>>>(Wv, Wvt, 4096, 1024);
  transpose_w_kernel<<<dim3(128, 128), 256, 0, stream>>>(Wo, Wot, 4096, 4096);

  gemm_bt_kernel<u16><<<dim3(32, 32), 256, 0, stream>>>(xb, Wqt, qb, 4096, 4096);
  gemm_bt_kernel<u16><<<dim3(8, 32), 256, 0, stream>>>(xb, Wkt, kb, 1024, 4096);
  gemm_bt_kernel<u16><<<dim3(8, 32), 256, 0, stream>>>(xb, Wvt, vb, 1024, 4096);

  rope_kernel<<<40960, 256, 0, stream>>>(qb, kb, cosp, sinp);

  attn_kernel<<<dim3(32, 32, 2), 256, 0, stream>>>(qb, kb, vb, ctx);

  gemm_bt_kernel<float><<<dim3(32, 32), 256, 0, stream>>>(ctx, Wot, (float*)d_out, 4096, 4096);
}

// Round 2
// 853.995 us; speedup vs baseline: 1.1106x; 1.1106x over previous
//
#include <hip/hip_runtime.h>
#include <stdint.h>

typedef unsigned short u16;
typedef __bf16 bf16x8 __attribute__((ext_vector_type(8)));
typedef float f32x4 __attribute__((ext_vector_type(4)));

#define D_MODEL 4096
#define T_SEQ   2048
#define B_SZ    2
#define NH      32
#define NKV     8
#define HDIM    128
#define WINDOW  1024
#define NGLOB   32

static constexpr float SCALE = 0.08838834764831845f; // 1/sqrt(128)

__device__ __forceinline__ u16 f2b(float f) {
  __bf16 h = (__bf16)f;
  return __builtin_bit_cast(u16, h);
}
__device__ __forceinline__ float b2f(u16 u) {
  return (float)__builtin_bit_cast(__bf16, u);
}

// ---------------- x f32 -> bf16 (vectorized) ----------------
__global__ __launch_bounds__(256) void convert_bf16_kernel(const float* __restrict__ in,
                                                           u16* __restrict__ outp, int n4) {
  int i = blockIdx.x * 256 + threadIdx.x;
  if (i >= n4) return;
  float4 v = ((const float4*)in)[i];
  ushort4 o;
  o.x = f2b(v.x); o.y = f2b(v.y); o.z = f2b(v.z); o.w = f2b(v.w);
  ((ushort4*)outp)[i] = o;
}

// ---------------- W [K,N] f32 -> Wt [N,K] bf16 ----------------
__global__ __launch_bounds__(256) void transpose_w_kernel(const float* __restrict__ W,
                                                          u16* __restrict__ Wt, int Kd, int Nd) {
  __shared__ float tile[32][33];
  int tx = threadIdx.x & 31, ty = threadIdx.x >> 5;
  int bx = blockIdx.x * 32; // N
  int by = blockIdx.y * 32; // K
#pragma unroll
  for (int i = 0; i < 4; ++i)
    tile[ty + i * 8][tx] = W[(size_t)(by + ty + i * 8) * Nd + bx + tx];
  __syncthreads();
#pragma unroll
  for (int i = 0; i < 4; ++i)
    Wt[(size_t)(bx + ty + i * 8) * Kd + by + tx] = f2b(tile[tx][ty + i * 8]);
}

// ---------------- v [B*T][KH*HD] bf16 -> vT [B][KH*HD][T] bf16 ----------------
__global__ __launch_bounds__(256) void transpose_v_kernel(const u16* __restrict__ in,
                                                          u16* __restrict__ outp) {
  __shared__ u16 tile[32][33];
  int tx = threadIdx.x & 31, ty = threadIdx.x >> 5;
  int x0 = blockIdx.x * 32; // hd' = kh*128+hd (0..1023)
  int t0 = blockIdx.y * 32; // t
  int b = blockIdx.z;
  const u16* src = in + (size_t)b * T_SEQ * (NKV * HDIM);
  u16* dst = outp + (size_t)b * (NKV * HDIM) * T_SEQ;
#pragma unroll
  for (int i = 0; i < 4; ++i)
    tile[ty + i * 8][tx] = src[(size_t)(t0 + ty + i * 8) * (NKV * HDIM) + x0 + tx];
  __syncthreads();
#pragma unroll
  for (int i = 0; i < 4; ++i)
    dst[(size_t)(x0 + ty + i * 8) * T_SEQ + t0 + tx] = tile[tx][ty + i * 8];
}

// ---------------- bf16 GEMM: C[M,N] = A[M,K] @ Bt[N,K]^T ----------------
// 128x128 tile, 4 waves (2x2), 4x4 16x16x32 frags/wave, global_load_lds width 16.
template <typename CT>
__global__ __launch_bounds__(256) void gemm_bt_kernel(const u16* __restrict__ A,
                                                      const u16* __restrict__ Bt,
                                                      CT* __restrict__ C, int N, int K) {
  __shared__ u16 As[128 * 32];
  __shared__ u16 Bs[128 * 32];
  int tid = threadIdx.x;
  int wave = tid >> 6, lane = tid & 63;
  int g = lane >> 4, li = lane & 15;
  int m0 = blockIdx.y * 128, n0 = blockIdx.x * 128;
  int wr = wave >> 1, wc = wave & 1;
  f32x4 zz = {0.f, 0.f, 0.f, 0.f};
  f32x4 acc[4][4];
#pragma unroll
  for (int m = 0; m < 4; ++m)
#pragma unroll
    for (int n = 0; n < 4; ++n) acc[m][n] = zz;

  for (int k0 = 0; k0 < K; k0 += 32) {
    __syncthreads(); // prior iter's LDS reads must drain before overwrite
#pragma unroll
    for (int i = 0; i < 2; ++i) {
      int instr = wave * 2 + i;
      int o = instr * 512 + lane * 8; // element offset within 128x32 tile
      int r = o >> 5, c = o & 31;
      const u16* gA = A + (size_t)(m0 + r) * K + k0 + c;
      const u16* gB = Bt + (size_t)(n0 + r) * K + k0 + c;
      __builtin_amdgcn_global_load_lds((__attribute__((address_space(1))) void*)gA,
                                       (__attribute__((address_space(3))) void*)(As + instr * 512),
                                       16, 0, 0);
      __builtin_amdgcn_global_load_lds((__attribute__((address_space(1))) void*)gB,
                                       (__attribute__((address_space(3))) void*)(Bs + instr * 512),
                                       16, 0, 0);
    }
    __syncthreads(); // compiler drains vmcnt(0) here
    bf16x8 af[4], bf[4];
#pragma unroll
    for (int m = 0; m < 4; ++m)
      af[m] = *(const bf16x8*)&As[(wr * 64 + m * 16 + li) * 32 + g * 8];
#pragma unroll
    for (int n = 0; n < 4; ++n)
      bf[n] = *(const bf16x8*)&Bs[(wc * 64 + n * 16 + li) * 32 + g * 8];
#pragma unroll
    for (int m = 0; m < 4; ++m)
#pragma unroll
      for (int n = 0; n < 4; ++n)
        acc[m][n] = __builtin_amdgcn_mfma_f32_16x16x32_bf16(af[m], bf[n], acc[m][n], 0, 0, 0);
  }
  // epilogue: C/D layout col=lane&15, row=(lane>>4)*4+reg (m89-verified)
#pragma unroll
  for (int m = 0; m < 4; ++m)
#pragma unroll
    for (int n = 0; n < 4; ++n)
#pragma unroll
      for (int r = 0; r < 4; ++r) {
        int row = m0 + wr * 64 + m * 16 + g * 4 + r;
        int col = n0 + wc * 64 + n * 16 + li;
        if constexpr (sizeof(CT) == 2)
          C[(size_t)row * N + col] = (CT)f2b(acc[m][n][r]);
        else
          C[(size_t)row * N + col] = acc[m][n][r];
      }
}

// ---------------- RoPE in place on bf16 q,k ----------------
__global__ __launch_bounds__(256) void rope_kernel(u16* __restrict__ qb, u16* __restrict__ kb,
                                                   const float* __restrict__ cosp,
                                                   const float* __restrict__ sinp) {
  int idx = blockIdx.x * 256 + threadIdx.x; // total B*T*(NH+NKV)*64
  int d = idx & 63;
  int rest = idx >> 6;
  int hh = rest % (NH + NKV);
  int bt = rest / (NH + NKV);
  if (bt >= B_SZ * T_SEQ) return;
  int tok = bt & (T_SEQ - 1);
  float c = cosp[tok * HDIM + d], s = sinp[tok * HDIM + d]; // table duplicated at d+64
  u16* base = (hh < NH) ? (qb + (size_t)bt * (NH * HDIM) + hh * HDIM)
                        : (kb + (size_t)bt * (NKV * HDIM) + (hh - NH) * HDIM);
  float x1 = b2f(base[d]), x2 = b2f(base[d + 64]);
  base[d] = f2b(x1 * c - x2 * s);
  base[d + 64] = f2b(x2 * c + x1 * s);
}

// ---------------- flash attention, QB=64 (4 waves x 16 rows), KVB=64 ----------------
// K staged row-major [64][128] (XOR swizzle on key row); V staged hd-major [128][64]
// from the pre-transposed vT (XOR swizzle on hd row) so PV B-frags are ds_read_b128.
__global__ __launch_bounds__(256) void attn_kernel(const u16* __restrict__ qp,
                                                   const u16* __restrict__ kp,
                                                   const u16* __restrict__ vtp,
                                                   u16* __restrict__ ctx) {
  __shared__ u16 Kt[64 * 128];
  __shared__ u16 Vt[128 * 64];
  __shared__ u16 Pl[4][16 * 64]; // per-wave P bounce, swizzled
  int tid = threadIdx.x;
  int w = tid >> 6, lane = tid & 63;
  int g = lane >> 4, li = lane & 15;
  int i0 = blockIdx.x * 64;
  int h = blockIdx.y, b = blockIdx.z;
  int kh = h >> 2; // repeat_interleave: q-head h -> kv-head h/4
  f32x4 zz = {0.f, 0.f, 0.f, 0.f};

  // Q fragments in registers (A-frag: row=li, k=g*8+e within 32-chunk c)
  bf16x8 qf[4];
  size_t qrow = (size_t)(b * T_SEQ + i0 + w * 16 + li) * (NH * HDIM) + h * HDIM;
#pragma unroll
  for (int c = 0; c < 4; ++c) qf[c] = *(const bf16x8*)(qp + qrow + c * 32 + g * 8);

  f32x4 o[8];
#pragma unroll
  for (int f = 0; f < 8; ++f) o[f] = zz;
  float m_s[4] = {-1e30f, -1e30f, -1e30f, -1e30f};
  float l_s[4] = {0.f, 0.f, 0.f, 0.f};

  int jmax = i0 + 63;
  for (int j0 = 0; j0 <= jmax; j0 += 64) {
    if (!((j0 < NGLOB) || (j0 + 63 > i0 - WINDOW))) continue; // fully-masked tile (block-uniform)
    __syncthreads();
    // stage K [64][128] and V^T [128][64], both XOR-swizzled (G4 recipe)
#pragma unroll
    for (int i = 0; i < 4; ++i) {
      int o8 = tid + 256 * i;
      int krow = o8 >> 4, kch = o8 & 15;
      size_t gk = (size_t)(b * T_SEQ + j0 + krow) * (NKV * HDIM) + kh * HDIM + kch * 8;
      *(bf16x8*)&Kt[(krow * 128 + kch * 8) ^ ((krow & 7) << 3)] = *(const bf16x8*)(kp + gk);
      int vrow = o8 >> 3, vch = o8 & 7; // vrow = hd
      size_t gv = ((size_t)(b * NKV + kh) * HDIM + vrow) * T_SEQ + j0 + vch * 8;
      *(bf16x8*)&Vt[(vrow * 64 + vch * 8) ^ ((vrow & 7) << 3)] = *(const bf16x8*)(vtp + gv);
    }
    __syncthreads();

    // S = Q @ K^T : 4 key-blocks of 16
    f32x4 s[4];
#pragma unroll
    for (int kb = 0; kb < 4; ++kb) s[kb] = zz;
#pragma unroll
    for (int c = 0; c < 4; ++c) {
      int hd0 = c * 32 + g * 8;
#pragma unroll
      for (int kb = 0; kb < 4; ++kb) {
        int key = kb * 16 + li;
        bf16x8 kf = *(const bf16x8*)&Kt[(key * 128 + hd0) ^ ((key & 7) << 3)];
        s[kb] = __builtin_amdgcn_mfma_f32_16x16x32_bf16(qf[c], kf, s[kb], 0, 0, 0);
      }
    }

    // mask + online softmax (rows g*4+r, cols kb*16+li); write P to swizzled LDS
    float corr[4];
#pragma unroll
    for (int r = 0; r < 4; ++r) {
      int irow = i0 + w * 16 + g * 4 + r;
      float x[4];
#pragma unroll
      for (int kb = 0; kb < 4; ++kb) {
        int j = j0 + kb * 16 + li;
        float xx = s[kb][r] * SCALE;
        bool vm = (j <= irow) && ((j > irow - WINDOW) || (j < NGLOB));
        x[kb] = vm ? xx : -1e30f;
      }
      float mt = fmaxf(fmaxf(x[0], x[1]), fmaxf(x[2], x[3]));
#pragma unroll
      for (int dd = 1; dd < 16; dd <<= 1) mt = fmaxf(mt, __shfl_xor(mt, dd, 64));
      float mn = fmaxf(m_s[r], mt);
      corr[r] = __expf(m_s[r] - mn);
      m_s[r] = mn;
      float rs = 0.f;
      int prow = g * 4 + r;
#pragma unroll
      for (int kb = 0; kb < 4; ++kb) {
        x[kb] = __expf(x[kb] - mn);
        rs += x[kb];
        Pl[w][(prow * 64 + kb * 16 + li) ^ ((prow & 7) << 3)] = f2b(x[kb]);
      }
#pragma unroll
      for (int dd = 1; dd < 16; dd <<= 1) rs += __shfl_xor(rs, dd, 64);
      l_s[r] = l_s[r] * corr[r] + rs;
    }
#pragma unroll
    for (int f = 0; f < 8; ++f) {
      o[f][0] *= corr[0]; o[f][1] *= corr[1];
      o[f][2] *= corr[2]; o[f][3] *= corr[3];
    }

    // P A-frags (row=li): two k-chunks of 32
    bf16x8 pa0 = *(const bf16x8*)&Pl[w][(li * 64 + 0 + g * 8) ^ ((li & 7) << 3)];
    bf16x8 pa1 = *(const bf16x8*)&Pl[w][(li * 64 + 32 + g * 8) ^ ((li & 7) << 3)];

    // O += P @ V : B-frags are vector reads from hd-major Vt
#pragma unroll
    for (int f = 0; f < 8; ++f) {
      int hd = f * 16 + li;
      bf16x8 v0 = *(const bf16x8*)&Vt[(hd * 64 + 0 + g * 8) ^ ((li & 7) << 3)];
      bf16x8 v1 = *(const bf16x8*)&Vt[(hd * 64 + 32 + g * 8) ^ ((li & 7) << 3)];
      o[f] = __builtin_amdgcn_mfma_f32_16x16x32_bf16(pa0, v0, o[f], 0, 0, 0);
      o[f] = __builtin_amdgcn_mfma_f32_16x16x32_bf16(pa1, v1, o[f], 0, 0, 0);
    }
  }

  // epilogue: ctx[b*T+i][h*128+hd] bf16
#pragma unroll
  for (int f = 0; f < 8; ++f)
#pragma unroll
    for (int r = 0; r < 4; ++r) {
      size_t orow = (size_t)(b * T_SEQ + i0 + w * 16 + g * 4 + r) * (NH * HDIM) + h * HDIM + f * 16 + li;
      ctx[orow] = f2b(o[f][r] / l_s[r]);
    }
}

extern "C" void kernel_launch(void* const* d_in, const int* in_sizes, int n_in,
                              void* d_out, int out_size, void* d_ws, size_t ws_size,
                              hipStream_t stream) {
  const float* x    = (const float*)d_in[0];
  const float* Wq   = (const float*)d_in[1];
  const float* Wk   = (const float*)d_in[2];
  const float* Wv   = (const float*)d_in[3];
  const float* Wo   = (const float*)d_in[4];
  const float* cosp = (const float*)d_in[5];
  const float* sinp = (const float*)d_in[6];
  // d_in[7] = mask: recomputed analytically in-kernel.

  char* ws = (char*)d_ws;
  // ws layout (bytes); ctx aliases xb (dead after QKV GEMMs); vT aliases Wqt
  // (dead after Q GEMM). All reuse is stream-ordered.
  u16* xb  = (u16*)(ws + 0ull);          // 32 MiB  [4096,4096] bf16
  u16* Wqt = (u16*)(ws + 33554432ull);   // 32 MiB  [4096,4096]
  u16* Wkt = (u16*)(ws + 67108864ull);   // 8 MiB   [1024,4096]
  u16* Wvt = (u16*)(ws + 75497472ull);   // 8 MiB
  u16* Wot = (u16*)(ws + 83886080ull);   // 32 MiB
  u16* qb  = (u16*)(ws + 117440512ull);  // 32 MiB  [B*T, H*HD]
  u16* kb  = (u16*)(ws + 150994944ull);  // 8 MiB   [B*T, KH*HD]
  u16* vb  = (u16*)(ws + 159383552ull);  // 8 MiB   -> total 160 MiB
  u16* ctx = xb;
  u16* vT  = Wqt; // 8 MiB [B][KH*HD][T], written after Q-GEMM consumed Wqt

  convert_bf16_kernel<<<16384, 256, 0, stream>>>(x, xb, 4194304);
  transpose_w_kernel<<<dim3(128, 128), 256, 0, stream>>>(Wq, Wqt, 4096, 4096);
  transpose_w_kernel<<<dim3(32, 128), 256, 0, stream>>>(Wk, Wkt, 4096, 1024);
  transpose_w_kernel<<<dim3(32, 128), 256, 0, stream>>>(Wv, Wvt, 4096, 1024);
  transpose_w_kernel<<<dim3(128, 128), 256, 0, stream>>>(Wo, Wot, 4096, 4096);

  gemm_bt_kernel<u16><<<dim3(32, 32), 256, 0, stream>>>(xb, Wqt, qb, 4096, 4096);
  gemm_bt_kernel<u16><<<dim3(8, 32), 256, 0, stream>>>(xb, Wkt, kb, 1024, 4096);
  gemm_bt_kernel<u16><<<dim3(8, 32), 256, 0, stream>>>(xb, Wvt, vb, 1024, 4096);

  transpose_v_kernel<<<dim3(32, 64, 2), 256, 0, stream>>>(vb, vT);

  rope_kernel<<<40960, 256, 0, stream>>>(qb, kb, cosp, sinp);

  attn_kernel<<<dim3(32, 32, 2), 256, 0, stream>>>(qb, kb, vT, ctx);

  gemm_bt_kernel<float><<<dim3(32, 32), 256, 0, stream>>>(ctx, Wot, (float*)d_out, 4096, 4096);
}

// Round 3
// 610.443 us; speedup vs baseline: 1.5537x; 1.3990x over previous
//
#include <hip/hip_runtime.h>
#include <stdint.h>

typedef unsigned short u16;
typedef __bf16 bf16x8 __attribute__((ext_vector_type(8)));
typedef float f32x4 __attribute__((ext_vector_type(4)));

#define D_MODEL 4096
#define T_SEQ   2048
#define B_SZ    2
#define NH      32
#define NKV     8
#define HDIM    128
#define WINDOW  1024
#define NGLOB   32
#define QSTR    6144   // fused qkv row stride: [q 4096 | k 1024 | v 1024]

static constexpr float SCALE = 0.08838834764831845f; // 1/sqrt(128)

__device__ __forceinline__ u16 f2b(float f) {
  __bf16 h = (__bf16)f;
  return __builtin_bit_cast(u16, h);
}
__device__ __forceinline__ float b2f(u16 u) {
  return (float)__builtin_bit_cast(__bf16, u);
}

// ---------------- x f32 -> bf16 (vectorized) ----------------
__global__ __launch_bounds__(256) void convert_bf16_kernel(const float* __restrict__ in,
                                                           u16* __restrict__ outp, int n4) {
  int i = blockIdx.x * 256 + threadIdx.x;
  if (i >= n4) return;
  float4 v = ((const float4*)in)[i];
  ushort4 o;
  o.x = f2b(v.x); o.y = f2b(v.y); o.z = f2b(v.z); o.w = f2b(v.w);
  ((ushort4*)outp)[i] = o;
}

// ---------------- W [K,N] f32 -> Wt [N,K] bf16 ----------------
__global__ __launch_bounds__(256) void transpose_w_kernel(const float* __restrict__ W,
                                                          u16* __restrict__ Wt, int Kd, int Nd) {
  __shared__ float tile[32][33];
  int tx = threadIdx.x & 31, ty = threadIdx.x >> 5;
  int bx = blockIdx.x * 32; // N
  int by = blockIdx.y * 32; // K
#pragma unroll
  for (int i = 0; i < 4; ++i)
    tile[ty + i * 8][tx] = W[(size_t)(by + ty + i * 8) * Nd + bx + tx];
  __syncthreads();
#pragma unroll
  for (int i = 0; i < 4; ++i)
    Wt[(size_t)(bx + ty + i * 8) * Kd + by + tx] = f2b(tile[tx][ty + i * 8]);
}

// ---------------- v slice of qkv -> vT [B][KH*HD][T] bf16 ----------------
__global__ __launch_bounds__(256) void transpose_v_kernel(const u16* __restrict__ in,
                                                          u16* __restrict__ outp) {
  __shared__ u16 tile[32][33];
  int tx = threadIdx.x & 31, ty = threadIdx.x >> 5;
  int x0 = blockIdx.x * 32; // hd' = kh*128+hd (0..1023)
  int t0 = blockIdx.y * 32; // t
  int b = blockIdx.z;
  const u16* src = in + (size_t)b * T_SEQ * QSTR;
  u16* dst = outp + (size_t)b * (NKV * HDIM) * T_SEQ;
#pragma unroll
  for (int i = 0; i < 4; ++i)
    tile[ty + i * 8][tx] = src[(size_t)(t0 + ty + i * 8) * QSTR + x0 + tx];
  __syncthreads();
#pragma unroll
  for (int i = 0; i < 4; ++i)
    dst[(size_t)(x0 + ty + i * 8) * T_SEQ + t0 + tx] = tile[tx][ty + i * 8];
}

// ---------------- 256x256 8-phase bf16 GEMM: C = A[M,K] @ Bt[N,K]^T ----------------
// 8 waves (2Mx4N), per-wave 128x64 (acc[8][4]); BK=64; LDS 128 KiB dbuf;
// T2 xor-swizzle ((row&7)<<4 on bytes) via pre-swizzled global source;
// T3/T4 4-phase/K-tile with counted vmcnt(6); T5 setprio around MFMA.
template <typename CT>
__global__ __launch_bounds__(512, 2) void gemm256_kernel(const u16* __restrict__ A,
                                                         const u16* __restrict__ Bt,
                                                         CT* __restrict__ C,
                                                         int ldc, int K) {
  __shared__ u16 sh[65536]; // [buf:2][A 16384 | B 16384] u16 = 128 KiB
  const int tid = threadIdx.x;
  const int wave = tid >> 6, lane = tid & 63;
  const int g = lane >> 4, li = lane & 15;
  const int wr = wave >> 2, wc = wave & 3;
  const int m0 = blockIdx.y * 256, n0 = blockIdx.x * 256;
  // staging: thread covers rows r0, r0+64 of a 128x64 half at slot cs (pre-swizzled)
  const int r0 = tid >> 3;
  const int cs = ((tid & 7) ^ ((tid >> 3) & 7)) << 3;
  const u16* pA = A + (size_t)(m0 + r0) * K + cs;
  const u16* pB = Bt + (size_t)(n0 + r0) * K + cs;
  // fragment-read swizzled k-slots (row&7 == li&7 for all frag rows)
  const int sl0 = (g ^ (li & 7)) << 3;
  const int sl1 = ((4 + g) ^ (li & 7)) << 3;
  const int nT = K >> 6;

  f32x4 acc[8][4];
  f32x4 zz = {0.f, 0.f, 0.f, 0.f};
#pragma unroll
  for (int M = 0; M < 8; ++M)
#pragma unroll
    for (int n = 0; n < 4; ++n) acc[M][n] = zz;

  auto stage = [&](const u16* src0, int ts, int dstBase) {
#pragma unroll
    for (int i = 0; i < 2; ++i) {
      const u16* s = src0 + (size_t)(i * 64) * K + ts * 64;
      __builtin_amdgcn_global_load_lds((__attribute__((address_space(1))) void*)s,
                                       (__attribute__((address_space(3))) void*)(sh + dstBase + i * 4096 + wave * 512),
                                       16, 0, 0);
    }
  };

  // prologue: tile0 fully + tile1 {B0,B1,A0}; A1(1) is staged in t=0 phase 0.
  stage(pA, 0, 0);
  stage(pA + (size_t)128 * K, 0, 8192);
  stage(pB, 0, 16384);
  stage(pB + (size_t)128 * K, 0, 24576);
  stage(pB, 1, 32768 + 16384);
  stage(pB + (size_t)128 * K, 1, 32768 + 24576);
  stage(pA, 1, 32768);
  asm volatile("s_waitcnt vmcnt(6)" ::: "memory");
  __builtin_amdgcn_s_barrier();

  bf16x8 afr[4][2], bfr[4][2];
  for (int t = 0; t < nT; ++t) {
    const int cur = t & 1;
    const int ab = cur * 32768, bb = ab + 16384;
    const int nb = (cur ^ 1) * 32768;
    const int tn1 = (t + 1 < nT) ? t + 1 : nT - 1;
    const int tn2 = (t + 2 < nT) ? t + 2 : nT - 1;
    // ---- phase 0: read B(all)+A(half0); stage A1(t+1)->other buf ----
#pragma unroll
    for (int n = 0; n < 4; ++n) {
      int row = wc * 64 + n * 16 + li;
      bfr[n][0] = *(const bf16x8*)&sh[bb + row * 64 + sl0];
      bfr[n][1] = *(const bf16x8*)&sh[bb + row * 64 + sl1];
    }
#pragma unroll
    for (int m = 0; m < 4; ++m) {
      int row = wr * 128 + m * 16 + li;
      afr[m][0] = *(const bf16x8*)&sh[ab + row * 64 + sl0];
      afr[m][1] = *(const bf16x8*)&sh[ab + row * 64 + sl1];
    }
    stage(pA + (size_t)128 * K, tn1, nb + 8192);
    __builtin_amdgcn_s_barrier();
    asm volatile("s_waitcnt lgkmcnt(0)" ::: "memory");
    __builtin_amdgcn_sched_barrier(0);
    __builtin_amdgcn_s_setprio(1);
#pragma unroll
    for (int m = 0; m < 4; ++m)
#pragma unroll
      for (int n = 0; n < 2; ++n) {
        acc[m][n] = __builtin_amdgcn_mfma_f32_16x16x32_bf16(afr[m][0], bfr[n][0], acc[m][n], 0, 0, 0);
        acc[m][n] = __builtin_amdgcn_mfma_f32_16x16x32_bf16(afr[m][1], bfr[n][1], acc[m][n], 0, 0, 0);
      }
    __builtin_amdgcn_s_setprio(0);
    __builtin_amdgcn_s_barrier();
    // ---- phase 1: stage B0(t+2)->cur (B dead after p0) ----
    stage(pB, tn2, bb);
    __builtin_amdgcn_s_barrier();
    __builtin_amdgcn_s_setprio(1);
#pragma unroll
    for (int m = 0; m < 4; ++m)
#pragma unroll
      for (int n = 2; n < 4; ++n) {
        acc[m][n] = __builtin_amdgcn_mfma_f32_16x16x32_bf16(afr[m][0], bfr[n][0], acc[m][n], 0, 0, 0);
        acc[m][n] = __builtin_amdgcn_mfma_f32_16x16x32_bf16(afr[m][1], bfr[n][1], acc[m][n], 0, 0, 0);
      }
    __builtin_amdgcn_s_setprio(0);
    __builtin_amdgcn_s_barrier();
    // ---- phase 2: read A(half1); stage B1(t+2) ----
#pragma unroll
    for (int m = 0; m < 4; ++m) {
      int row = wr * 128 + 64 + m * 16 + li;
      afr[m][0] = *(const bf16x8*)&sh[ab + row * 64 + sl0];
      afr[m][1] = *(const bf16x8*)&sh[ab + row * 64 + sl1];
    }
    stage(pB + (size_t)128 * K, tn2, bb + 8192);
    __builtin_amdgcn_s_barrier();
    asm volatile("s_waitcnt lgkmcnt(0)" ::: "memory");
    __builtin_amdgcn_sched_barrier(0);
    __builtin_amdgcn_s_setprio(1);
#pragma unroll
    for (int m = 0; m < 4; ++m)
#pragma unroll
      for (int n = 0; n < 2; ++n) {
        acc[4 + m][n] = __builtin_amdgcn_mfma_f32_16x16x32_bf16(afr[m][0], bfr[n][0], acc[4 + m][n], 0, 0, 0);
        acc[4 + m][n] = __builtin_amdgcn_mfma_f32_16x16x32_bf16(afr[m][1], bfr[n][1], acc[4 + m][n], 0, 0, 0);
      }
    __builtin_amdgcn_s_setprio(0);
    __builtin_amdgcn_s_barrier();
    // ---- phase 3: stage A0(t+2) (A dead after p2); vmcnt(6) tile boundary ----
    stage(pA, tn2, ab);
    __builtin_amdgcn_s_barrier();
    __builtin_amdgcn_s_setprio(1);
#pragma unroll
    for (int m = 0; m < 4; ++m)
#pragma unroll
      for (int n = 2; n < 4; ++n) {
        acc[4 + m][n] = __builtin_amdgcn_mfma_f32_16x16x32_bf16(afr[m][0], bfr[n][0], acc[4 + m][n], 0, 0, 0);
        acc[4 + m][n] = __builtin_amdgcn_mfma_f32_16x16x32_bf16(afr[m][1], bfr[n][1], acc[4 + m][n], 0, 0, 0);
      }
    __builtin_amdgcn_s_setprio(0);
    asm volatile("s_waitcnt vmcnt(6)" ::: "memory");
    __builtin_amdgcn_s_barrier();
  }
  // epilogue: C/D layout col=lane&15, row=(lane>>4)*4+reg
#pragma unroll
  for (int M = 0; M < 8; ++M)
#pragma unroll
    for (int n = 0; n < 4; ++n)
#pragma unroll
      for (int r = 0; r < 4; ++r) {
        int row = m0 + wr * 128 + M * 16 + g * 4 + r;
        int col = n0 + wc * 64 + n * 16 + li;
        if constexpr (sizeof(CT) == 2)
          C[(size_t)row * ldc + col] = (CT)f2b(acc[M][n][r]);
        else
          C[(size_t)row * ldc + col] = acc[M][n][r];
      }
}

// ---------------- RoPE in place on fused qkv (q heads 0..31, k at col 4096) ----------------
__global__ __launch_bounds__(256) void rope_kernel(u16* __restrict__ qkv,
                                                   const float* __restrict__ cosp,
                                                   const float* __restrict__ sinp) {
  int idx = blockIdx.x * 256 + threadIdx.x; // B*T*(NH+NKV)*64
  int d = idx & 63;
  int rest = idx >> 6;
  int hh = rest % (NH + NKV);
  int bt = rest / (NH + NKV);
  if (bt >= B_SZ * T_SEQ) return;
  int tok = bt & (T_SEQ - 1);
  float c = cosp[tok * HDIM + d], s = sinp[tok * HDIM + d]; // table duplicated at d+64
  // q head hh<32 at col hh*128; k head (hh-32) at col 4096+(hh-32)*128 == hh*128
  u16* base = qkv + (size_t)bt * QSTR + hh * HDIM;
  float x1 = b2f(base[d]), x2 = b2f(base[d + 64]);
  base[d] = f2b(x1 * c - x2 * s);
  base[d + 64] = f2b(x2 * c + x1 * s);
}

// ---------------- flash attention, QB=64 (4 waves x 16 rows), KVB=64 ----------------
__global__ __launch_bounds__(256) void attn_kernel(const u16* __restrict__ qp,
                                                   const u16* __restrict__ kp,
                                                   const u16* __restrict__ vtp,
                                                   u16* __restrict__ ctx) {
  __shared__ u16 Kt[64 * 128];
  __shared__ u16 Vt[128 * 64];
  __shared__ u16 Pl[4][16 * 64]; // per-wave P bounce, swizzled
  int tid = threadIdx.x;
  int w = tid >> 6, lane = tid & 63;
  int g = lane >> 4, li = lane & 15;
  int i0 = blockIdx.x * 64;
  int h = blockIdx.y, b = blockIdx.z;
  int kh = h >> 2; // repeat_interleave: q-head h -> kv-head h/4
  f32x4 zz = {0.f, 0.f, 0.f, 0.f};

  bf16x8 qf[4];
  size_t qrow = (size_t)(b * T_SEQ + i0 + w * 16 + li) * QSTR + h * HDIM;
#pragma unroll
  for (int c = 0; c < 4; ++c) qf[c] = *(const bf16x8*)(qp + qrow + c * 32 + g * 8);

  f32x4 o[8];
#pragma unroll
  for (int f = 0; f < 8; ++f) o[f] = zz;
  float m_s[4] = {-1e30f, -1e30f, -1e30f, -1e30f};
  float l_s[4] = {0.f, 0.f, 0.f, 0.f};

  int jmax = i0 + 63;
  for (int j0 = 0; j0 <= jmax; j0 += 64) {
    if (!((j0 < NGLOB) || (j0 + 63 > i0 - WINDOW))) continue; // fully-masked tile
    __syncthreads();
#pragma unroll
    for (int i = 0; i < 4; ++i) {
      int o8 = tid + 256 * i;
      int krow = o8 >> 4, kch = o8 & 15;
      size_t gk = (size_t)(b * T_SEQ + j0 + krow) * QSTR + kh * HDIM + kch * 8;
      *(bf16x8*)&Kt[(krow * 128 + kch * 8) ^ ((krow & 7) << 3)] = *(const bf16x8*)(kp + gk);
      int vrow = o8 >> 3, vch = o8 & 7; // vrow = hd
      size_t gv = ((size_t)(b * NKV + kh) * HDIM + vrow) * T_SEQ + j0 + vch * 8;
      *(bf16x8*)&Vt[(vrow * 64 + vch * 8) ^ ((vrow & 7) << 3)] = *(const bf16x8*)(vtp + gv);
    }
    __syncthreads();

    f32x4 s[4];
#pragma unroll
    for (int kb = 0; kb < 4; ++kb) s[kb] = zz;
#pragma unroll
    for (int c = 0; c < 4; ++c) {
      int hd0 = c * 32 + g * 8;
#pragma unroll
      for (int kb = 0; kb < 4; ++kb) {
        int key = kb * 16 + li;
        bf16x8 kf = *(const bf16x8*)&Kt[(key * 128 + hd0) ^ ((key & 7) << 3)];
        s[kb] = __builtin_amdgcn_mfma_f32_16x16x32_bf16(qf[c], kf, s[kb], 0, 0, 0);
      }
    }

    float corr[4];
#pragma unroll
    for (int r = 0; r < 4; ++r) {
      int irow = i0 + w * 16 + g * 4 + r;
      float x[4];
#pragma unroll
      for (int kb = 0; kb < 4; ++kb) {
        int j = j0 + kb * 16 + li;
        float xx = s[kb][r] * SCALE;
        bool vm = (j <= irow) && ((j > irow - WINDOW) || (j < NGLOB));
        x[kb] = vm ? xx : -1e30f;
      }
      float mt = fmaxf(fmaxf(x[0], x[1]), fmaxf(x[2], x[3]));
#pragma unroll
      for (int dd = 1; dd < 16; dd <<= 1) mt = fmaxf(mt, __shfl_xor(mt, dd, 64));
      float mn = fmaxf(m_s[r], mt);
      corr[r] = __expf(m_s[r] - mn);
      m_s[r] = mn;
      float rs = 0.f;
      int prow = g * 4 + r;
#pragma unroll
      for (int kb = 0; kb < 4; ++kb) {
        x[kb] = __expf(x[kb] - mn);
        rs += x[kb];
        Pl[w][(prow * 64 + kb * 16 + li) ^ ((prow & 7) << 3)] = f2b(x[kb]);
      }
#pragma unroll
      for (int dd = 1; dd < 16; dd <<= 1) rs += __shfl_xor(rs, dd, 64);
      l_s[r] = l_s[r] * corr[r] + rs;
    }
#pragma unroll
    for (int f = 0; f < 8; ++f) {
      o[f][0] *= corr[0]; o[f][1] *= corr[1];
      o[f][2] *= corr[2]; o[f][3] *= corr[3];
    }

    bf16x8 pa0 = *(const bf16x8*)&Pl[w][(li * 64 + 0 + g * 8) ^ ((li & 7) << 3)];
    bf16x8 pa1 = *(const bf16x8*)&Pl[w][(li * 64 + 32 + g * 8) ^ ((li & 7) << 3)];

#pragma unroll
    for (int f = 0; f < 8; ++f) {
      int hd = f * 16 + li;
      bf16x8 v0 = *(const bf16x8*)&Vt[(hd * 64 + 0 + g * 8) ^ ((li & 7) << 3)];
      bf16x8 v1 = *(const bf16x8*)&Vt[(hd * 64 + 32 + g * 8) ^ ((li & 7) << 3)];
      o[f] = __builtin_amdgcn_mfma_f32_16x16x32_bf16(pa0, v0, o[f], 0, 0, 0);
      o[f] = __builtin_amdgcn_mfma_f32_16x16x32_bf16(pa1, v1, o[f], 0, 0, 0);
    }
  }

#pragma unroll
  for (int f = 0; f < 8; ++f)
#pragma unroll
    for (int r = 0; r < 4; ++r) {
      size_t orow = (size_t)(b * T_SEQ + i0 + w * 16 + g * 4 + r) * (NH * HDIM) + h * HDIM + f * 16 + li;
      ctx[orow] = f2b(o[f][r] / l_s[r]);
    }
}

extern "C" void kernel_launch(void* const* d_in, const int* in_sizes, int n_in,
                              void* d_out, int out_size, void* d_ws, size_t ws_size,
                              hipStream_t stream) {
  const float* x    = (const float*)d_in[0];
  const float* Wq   = (const float*)d_in[1];
  const float* Wk   = (const float*)d_in[2];
  const float* Wv   = (const float*)d_in[3];
  const float* Wo   = (const float*)d_in[4];
  const float* cosp = (const float*)d_in[5];
  const float* sinp = (const float*)d_in[6];
  // d_in[7] = mask: recomputed analytically in-kernel.

  char* ws = (char*)d_ws;
  // ws layout (160 MiB total); aliasing is stream-ordered:
  //   ctx aliases xb (dead after QKV GEMM); vT aliases Wqkvt (dead after QKV GEMM)
  u16* xb     = (u16*)(ws + 0ull);           // 32 MiB [4096,4096]
  u16* Wqkvt  = (u16*)(ws + 33554432ull);    // 48 MiB [6144,4096]
  u16* Wot    = (u16*)(ws + 83886080ull);    // 32 MiB [4096,4096]
  u16* qkv    = (u16*)(ws + 117440512ull);   // 48 MiB [4096,6144]
  u16* ctx    = xb;
  u16* vT     = Wqkvt;                        // 8 MiB [B][KH*HD][T]

  convert_bf16_kernel<<<16384, 256, 0, stream>>>(x, xb, 4194304);
  transpose_w_kernel<<<dim3(128, 128), 256, 0, stream>>>(Wq, Wqkvt, 4096, 4096);
  transpose_w_kernel<<<dim3(32, 128), 256, 0, stream>>>(Wk, Wqkvt + (size_t)4096 * 4096, 4096, 1024);
  transpose_w_kernel<<<dim3(32, 128), 256, 0, stream>>>(Wv, Wqkvt + (size_t)5120 * 4096, 4096, 1024);
  transpose_w_kernel<<<dim3(128, 128), 256, 0, stream>>>(Wo, Wot, 4096, 4096);

  // fused QKV projection: [4096,4096] @ [6144,4096]^T -> [4096,6144]
  gemm256_kernel<u16><<<dim3(24, 16), 512, 0, stream>>>(xb, Wqkvt, qkv, QSTR, 4096);

  transpose_v_kernel<<<dim3(32, 64, 2), 256, 0, stream>>>(qkv + 5120, vT);

  rope_kernel<<<40960, 256, 0, stream>>>(qkv, cosp, sinp);

  attn_kernel<<<dim3(32, 32, 2), 256, 0, stream>>>(qkv, qkv + 4096, vT, ctx);

  gemm256_kernel<float><<<dim3(16, 16), 512, 0, stream>>>(ctx, Wot, (float*)d_out, 4096, 4096);
}

// Round 4
// 577.420 us; speedup vs baseline: 1.6426x; 1.0572x over previous
//
#include <hip/hip_runtime.h>
#include <stdint.h>

typedef unsigned short u16;
typedef __bf16 bf16x8 __attribute__((ext_vector_type(8)));
typedef float f32x4 __attribute__((ext_vector_type(4)));

#define D_MODEL 4096
#define T_SEQ   2048
#define B_SZ    2
#define NH      32
#define NKV     8
#define HDIM    128
#define WINDOW  1024
#define NGLOB   32
#define QSTR    6144   // fused qkv row stride: [q 4096 | k 1024 | v 1024]

static constexpr float SCALE = 0.08838834764831845f; // 1/sqrt(128)

__device__ __forceinline__ u16 f2b(float f) {
  __bf16 h = (__bf16)f;
  return __builtin_bit_cast(u16, h);
}
__device__ __forceinline__ float b2f(u16 u) {
  return (float)__builtin_bit_cast(__bf16, u);
}

// ---------------- x f32 -> bf16 (vectorized) ----------------
__global__ __launch_bounds__(256) void convert_bf16_kernel(const float* __restrict__ in,
                                                           u16* __restrict__ outp, int n4) {
  int i = blockIdx.x * 256 + threadIdx.x;
  if (i >= n4) return;
  float4 v = ((const float4*)in)[i];
  ushort4 o;
  o.x = f2b(v.x); o.y = f2b(v.y); o.z = f2b(v.z); o.w = f2b(v.w);
  ((ushort4*)outp)[i] = o;
}

// ---------------- W [K,N] f32 -> Wt [N,K] bf16 ----------------
__global__ __launch_bounds__(256) void transpose_w_kernel(const float* __restrict__ W,
                                                          u16* __restrict__ Wt, int Kd, int Nd) {
  __shared__ float tile[32][33];
  int tx = threadIdx.x & 31, ty = threadIdx.x >> 5;
  int bx = blockIdx.x * 32; // N
  int by = blockIdx.y * 32; // K
#pragma unroll
  for (int i = 0; i < 4; ++i)
    tile[ty + i * 8][tx] = W[(size_t)(by + ty + i * 8) * Nd + bx + tx];
  __syncthreads();
#pragma unroll
  for (int i = 0; i < 4; ++i)
    Wt[(size_t)(bx + ty + i * 8) * Kd + by + tx] = f2b(tile[tx][ty + i * 8]);
}

// ---------------- v slice of qkv -> vT [B][KH*HD][T] bf16 ----------------
__global__ __launch_bounds__(256) void transpose_v_kernel(const u16* __restrict__ in,
                                                          u16* __restrict__ outp) {
  __shared__ u16 tile[32][33];
  int tx = threadIdx.x & 31, ty = threadIdx.x >> 5;
  int x0 = blockIdx.x * 32; // hd' = kh*128+hd (0..1023)
  int t0 = blockIdx.y * 32; // t
  int b = blockIdx.z;
  const u16* src = in + (size_t)b * T_SEQ * QSTR;
  u16* dst = outp + (size_t)b * (NKV * HDIM) * T_SEQ;
#pragma unroll
  for (int i = 0; i < 4; ++i)
    tile[ty + i * 8][tx] = src[(size_t)(t0 + ty + i * 8) * QSTR + x0 + tx];
  __syncthreads();
#pragma unroll
  for (int i = 0; i < 4; ++i)
    dst[(size_t)(x0 + ty + i * 8) * T_SEQ + t0 + tx] = tile[tx][ty + i * 8];
}

// ---------------- 256x256 8-phase bf16 GEMM (proven): C = A @ Bt^T ----------------
template <typename CT>
__global__ __launch_bounds__(512, 2) void gemm256_kernel(const u16* __restrict__ A,
                                                         const u16* __restrict__ Bt,
                                                         CT* __restrict__ C,
                                                         int ldc, int K) {
  __shared__ u16 sh[65536]; // [buf:2][A 16384 | B 16384] u16 = 128 KiB
  const int tid = threadIdx.x;
  const int wave = tid >> 6, lane = tid & 63;
  const int g = lane >> 4, li = lane & 15;
  const int wr = wave >> 2, wc = wave & 3;
  const int m0 = blockIdx.y * 256, n0 = blockIdx.x * 256;
  const int r0 = tid >> 3;
  const int cs = ((tid & 7) ^ ((tid >> 3) & 7)) << 3;
  const u16* pA = A + (size_t)(m0 + r0) * K + cs;
  const u16* pB = Bt + (size_t)(n0 + r0) * K + cs;
  const int sl0 = (g ^ (li & 7)) << 3;
  const int sl1 = ((4 + g) ^ (li & 7)) << 3;
  const int nT = K >> 6;

  f32x4 acc[8][4];
  f32x4 zz = {0.f, 0.f, 0.f, 0.f};
#pragma unroll
  for (int M = 0; M < 8; ++M)
#pragma unroll
    for (int n = 0; n < 4; ++n) acc[M][n] = zz;

  auto stage = [&](const u16* src0, int ts, int dstBase) {
#pragma unroll
    for (int i = 0; i < 2; ++i) {
      const u16* s = src0 + (size_t)(i * 64) * K + ts * 64;
      __builtin_amdgcn_global_load_lds((__attribute__((address_space(1))) void*)s,
                                       (__attribute__((address_space(3))) void*)(sh + dstBase + i * 4096 + wave * 512),
                                       16, 0, 0);
    }
  };

  stage(pA, 0, 0);
  stage(pA + (size_t)128 * K, 0, 8192);
  stage(pB, 0, 16384);
  stage(pB + (size_t)128 * K, 0, 24576);
  stage(pB, 1, 32768 + 16384);
  stage(pB + (size_t)128 * K, 1, 32768 + 24576);
  stage(pA, 1, 32768);
  asm volatile("s_waitcnt vmcnt(6)" ::: "memory");
  __builtin_amdgcn_s_barrier();

  bf16x8 afr[4][2], bfr[4][2];
  for (int t = 0; t < nT; ++t) {
    const int cur = t & 1;
    const int ab = cur * 32768, bb = ab + 16384;
    const int nb = (cur ^ 1) * 32768;
    const int tn1 = (t + 1 < nT) ? t + 1 : nT - 1;
    const int tn2 = (t + 2 < nT) ? t + 2 : nT - 1;
#pragma unroll
    for (int n = 0; n < 4; ++n) {
      int row = wc * 64 + n * 16 + li;
      bfr[n][0] = *(const bf16x8*)&sh[bb + row * 64 + sl0];
      bfr[n][1] = *(const bf16x8*)&sh[bb + row * 64 + sl1];
    }
#pragma unroll
    for (int m = 0; m < 4; ++m) {
      int row = wr * 128 + m * 16 + li;
      afr[m][0] = *(const bf16x8*)&sh[ab + row * 64 + sl0];
      afr[m][1] = *(const bf16x8*)&sh[ab + row * 64 + sl1];
    }
    stage(pA + (size_t)128 * K, tn1, nb + 8192);
    __builtin_amdgcn_s_barrier();
    asm volatile("s_waitcnt lgkmcnt(0)" ::: "memory");
    __builtin_amdgcn_sched_barrier(0);
    __builtin_amdgcn_s_setprio(1);
#pragma unroll
    for (int m = 0; m < 4; ++m)
#pragma unroll
      for (int n = 0; n < 2; ++n) {
        acc[m][n] = __builtin_amdgcn_mfma_f32_16x16x32_bf16(afr[m][0], bfr[n][0], acc[m][n], 0, 0, 0);
        acc[m][n] = __builtin_amdgcn_mfma_f32_16x16x32_bf16(afr[m][1], bfr[n][1], acc[m][n], 0, 0, 0);
      }
    __builtin_amdgcn_s_setprio(0);
    __builtin_amdgcn_s_barrier();
    stage(pB, tn2, bb);
    __builtin_amdgcn_s_barrier();
    __builtin_amdgcn_s_setprio(1);
#pragma unroll
    for (int m = 0; m < 4; ++m)
#pragma unroll
      for (int n = 2; n < 4; ++n) {
        acc[m][n] = __builtin_amdgcn_mfma_f32_16x16x32_bf16(afr[m][0], bfr[n][0], acc[m][n], 0, 0, 0);
        acc[m][n] = __builtin_amdgcn_mfma_f32_16x16x32_bf16(afr[m][1], bfr[n][1], acc[m][n], 0, 0, 0);
      }
    __builtin_amdgcn_s_setprio(0);
    __builtin_amdgcn_s_barrier();
#pragma unroll
    for (int m = 0; m < 4; ++m) {
      int row = wr * 128 + 64 + m * 16 + li;
      afr[m][0] = *(const bf16x8*)&sh[ab + row * 64 + sl0];
      afr[m][1] = *(const bf16x8*)&sh[ab + row * 64 + sl1];
    }
    stage(pB + (size_t)128 * K, tn2, bb + 8192);
    __builtin_amdgcn_s_barrier();
    asm volatile("s_waitcnt lgkmcnt(0)" ::: "memory");
    __builtin_amdgcn_sched_barrier(0);
    __builtin_amdgcn_s_setprio(1);
#pragma unroll
    for (int m = 0; m < 4; ++m)
#pragma unroll
      for (int n = 0; n < 2; ++n) {
        acc[4 + m][n] = __builtin_amdgcn_mfma_f32_16x16x32_bf16(afr[m][0], bfr[n][0], acc[4 + m][n], 0, 0, 0);
        acc[4 + m][n] = __builtin_amdgcn_mfma_f32_16x16x32_bf16(afr[m][1], bfr[n][1], acc[4 + m][n], 0, 0, 0);
      }
    __builtin_amdgcn_s_setprio(0);
    __builtin_amdgcn_s_barrier();
    stage(pA, tn2, ab);
    __builtin_amdgcn_s_barrier();
    __builtin_amdgcn_s_setprio(1);
#pragma unroll
    for (int m = 0; m < 4; ++m)
#pragma unroll
      for (int n = 2; n < 4; ++n) {
        acc[4 + m][n] = __builtin_amdgcn_mfma_f32_16x16x32_bf16(afr[m][0], bfr[n][0], acc[4 + m][n], 0, 0, 0);
        acc[4 + m][n] = __builtin_amdgcn_mfma_f32_16x16x32_bf16(afr[m][1], bfr[n][1], acc[4 + m][n], 0, 0, 0);
      }
    __builtin_amdgcn_s_setprio(0);
    asm volatile("s_waitcnt vmcnt(6)" ::: "memory");
    __builtin_amdgcn_s_barrier();
  }
#pragma unroll
  for (int M = 0; M < 8; ++M)
#pragma unroll
    for (int n = 0; n < 4; ++n)
#pragma unroll
      for (int r = 0; r < 4; ++r) {
        int row = m0 + wr * 128 + M * 16 + g * 4 + r;
        int col = n0 + wc * 64 + n * 16 + li;
        if constexpr (sizeof(CT) == 2)
          C[(size_t)row * ldc + col] = (CT)f2b(acc[M][n][r]);
        else
          C[(size_t)row * ldc + col] = acc[M][n][r];
      }
}

// ---------------- 256x192 4-phase bf16 GEMM: packs N=6144 into 512 blocks ----------------
// Same rhythm as gemm256; 64-row stage units (A0..A3, B0..B2), full tile-(t+2)
// staging into dying regions, vmcnt(7) at tile boundary (7 units/tile, 2 ahead).
__global__ __launch_bounds__(512, 2) void gemm192_kernel(const u16* __restrict__ A,
                                                         const u16* __restrict__ Bt,
                                                         u16* __restrict__ C,
                                                         int ldc, int K) {
  __shared__ u16 sh[57344]; // dbuf x [A 16384 | B 12288] u16 = 112 KiB
  const int tid = threadIdx.x;
  const int wave = tid >> 6, lane = tid & 63;
  const int g = lane >> 4, li = lane & 15;
  const int wr = wave >> 2, wc = wave & 3;
  const int m0 = blockIdx.y * 256, n0 = blockIdx.x * 192;
  const int r0 = tid >> 3;
  const int cs = ((tid & 7) ^ ((tid >> 3) & 7)) << 3;
  const u16* pA = A + (size_t)(m0 + r0) * K + cs;
  const u16* pB = Bt + (size_t)(n0 + r0) * K + cs;
  const int sl0 = (g ^ (li & 7)) << 3;
  const int sl1 = ((4 + g) ^ (li & 7)) << 3;
  const int nT = K >> 6;

  f32x4 acc[8][3];
  f32x4 zz = {0.f, 0.f, 0.f, 0.f};
#pragma unroll
  for (int M = 0; M < 8; ++M)
#pragma unroll
    for (int n = 0; n < 3; ++n) acc[M][n] = zz;

  auto stage64 = [&](const u16* src0, int ts, int dstU16) {
    __builtin_amdgcn_global_load_lds(
        (__attribute__((address_space(1))) void*)(src0 + (size_t)ts * 64),
        (__attribute__((address_space(3))) void*)(sh + dstU16 + wave * 512), 16, 0, 0);
  };

  // prologue: tile0 (7 units) then tile1 (7 units); wait for tile0
#pragma unroll
  for (int u = 0; u < 4; ++u) stage64(pA + (size_t)(u * 64) * K, 0, u * 4096);
#pragma unroll
  for (int u = 0; u < 3; ++u) stage64(pB + (size_t)(u * 64) * K, 0, 16384 + u * 4096);
#pragma unroll
  for (int u = 0; u < 4; ++u) stage64(pA + (size_t)(u * 64) * K, 1, 28672 + u * 4096);
#pragma unroll
  for (int u = 0; u < 3; ++u) stage64(pB + (size_t)(u * 64) * K, 1, 28672 + 16384 + u * 4096);
  asm volatile("s_waitcnt vmcnt(7)" ::: "memory");
  __builtin_amdgcn_s_barrier();

  bf16x8 afr[4][2], bfr[3][2];
  for (int t = 0; t < nT; ++t) {
    const int ab = (t & 1) * 28672, bb = ab + 16384;
    const int tn2 = (t + 2 < nT) ? t + 2 : nT - 1;
    // ---- p0: read B(all) + A(half0); no stage (nothing dead yet) ----
#pragma unroll
    for (int n = 0; n < 3; ++n) {
      int row = wc * 48 + n * 16 + li;
      bfr[n][0] = *(const bf16x8*)&sh[bb + row * 64 + sl0];
      bfr[n][1] = *(const bf16x8*)&sh[bb + row * 64 + sl1];
    }
#pragma unroll
    for (int m = 0; m < 4; ++m) {
      int row = wr * 128 + m * 16 + li;
      afr[m][0] = *(const bf16x8*)&sh[ab + row * 64 + sl0];
      afr[m][1] = *(const bf16x8*)&sh[ab + row * 64 + sl1];
    }
    __builtin_amdgcn_s_barrier();
    asm volatile("s_waitcnt lgkmcnt(0)" ::: "memory");
    __builtin_amdgcn_sched_barrier(0);
    __builtin_amdgcn_s_setprio(1);
#pragma unroll
    for (int m = 0; m < 4; ++m)
#pragma unroll
      for (int n = 0; n < 2; ++n) {
        acc[m][n] = __builtin_amdgcn_mfma_f32_16x16x32_bf16(afr[m][0], bfr[n][0], acc[m][n], 0, 0, 0);
        acc[m][n] = __builtin_amdgcn_mfma_f32_16x16x32_bf16(afr[m][1], bfr[n][1], acc[m][n], 0, 0, 0);
      }
    __builtin_amdgcn_s_setprio(0);
    __builtin_amdgcn_s_barrier();
    // ---- p1: stage B0,B1,A0 (t+2 -> cur; all dead after p0) ----
    stage64(pB, tn2, bb);
    stage64(pB + (size_t)64 * K, tn2, bb + 4096);
    stage64(pA, tn2, ab);
    __builtin_amdgcn_s_barrier();
    __builtin_amdgcn_s_setprio(1);
#pragma unroll
    for (int m = 0; m < 4; ++m) {
      acc[m][2] = __builtin_amdgcn_mfma_f32_16x16x32_bf16(afr[m][0], bfr[2][0], acc[m][2], 0, 0, 0);
      acc[m][2] = __builtin_amdgcn_mfma_f32_16x16x32_bf16(afr[m][1], bfr[2][1], acc[m][2], 0, 0, 0);
    }
    __builtin_amdgcn_s_setprio(0);
    __builtin_amdgcn_s_barrier();
    // ---- p2: read A(half1); stage B2,A2 (dead after p0) ----
#pragma unroll
    for (int m = 0; m < 4; ++m) {
      int row = wr * 128 + 64 + m * 16 + li;
      afr[m][0] = *(const bf16x8*)&sh[ab + row * 64 + sl0];
      afr[m][1] = *(const bf16x8*)&sh[ab + row * 64 + sl1];
    }
    stage64(pB + (size_t)128 * K, tn2, bb + 8192);
    stage64(pA + (size_t)128 * K, tn2, ab + 8192);
    __builtin_amdgcn_s_barrier();
    asm volatile("s_waitcnt lgkmcnt(0)" ::: "memory");
    __builtin_amdgcn_sched_barrier(0);
    __builtin_amdgcn_s_setprio(1);
#pragma unroll
    for (int m = 0; m < 4; ++m)
#pragma unroll
      for (int n = 0; n < 2; ++n) {
        acc[4 + m][n] = __builtin_amdgcn_mfma_f32_16x16x32_bf16(afr[m][0], bfr[n][0], acc[4 + m][n], 0, 0, 0);
        acc[4 + m][n] = __builtin_amdgcn_mfma_f32_16x16x32_bf16(afr[m][1], bfr[n][1], acc[4 + m][n], 0, 0, 0);
      }
    __builtin_amdgcn_s_setprio(0);
    __builtin_amdgcn_s_barrier();
    // ---- p3: stage A1,A3 (half1 dead after p2); vmcnt(7) tile boundary ----
    stage64(pA + (size_t)64 * K, tn2, ab + 4096);
    stage64(pA + (size_t)192 * K, tn2, ab + 12288);
    __builtin_amdgcn_s_barrier();
    __builtin_amdgcn_s_setprio(1);
#pragma unroll
    for (int m = 0; m < 4; ++m) {
      acc[4 + m][2] = __builtin_amdgcn_mfma_f32_16x16x32_bf16(afr[m][0], bfr[2][0], acc[4 + m][2], 0, 0, 0);
      acc[4 + m][2] = __builtin_amdgcn_mfma_f32_16x16x32_bf16(afr[m][1], bfr[2][1], acc[4 + m][2], 0, 0, 0);
    }
    __builtin_amdgcn_s_setprio(0);
    asm volatile("s_waitcnt vmcnt(7)" ::: "memory");
    __builtin_amdgcn_s_barrier();
  }
  // epilogue
#pragma unroll
  for (int M = 0; M < 8; ++M)
#pragma unroll
    for (int n = 0; n < 3; ++n)
#pragma unroll
      for (int r = 0; r < 4; ++r) {
        int row = m0 + wr * 128 + M * 16 + g * 4 + r;
        int col = n0 + wc * 48 + n * 16 + li;
        C[(size_t)row * ldc + col] = f2b(acc[M][n][r]);
      }
}

// ---------------- RoPE in place on fused qkv, bf16x8-vectorized ----------------
__global__ __launch_bounds__(256) void rope_kernel(u16* __restrict__ qkv,
                                                   const float* __restrict__ cosp,
                                                   const float* __restrict__ sinp) {
  int idx = blockIdx.x * 256 + threadIdx.x; // B*T*(NH+NKV)*8
  int d8 = idx & 7;
  int rest = idx >> 3;
  int hh = rest % (NH + NKV);
  int bt = rest / (NH + NKV);
  if (bt >= B_SZ * T_SEQ) return;
  int tok = bt & (T_SEQ - 1);
  int d0 = d8 * 8;
  const float4* cp = (const float4*)(cosp + (size_t)tok * HDIM + d0);
  const float4* sp = (const float4*)(sinp + (size_t)tok * HDIM + d0);
  float4 cA = cp[0], cB = cp[1];
  float4 sA = sp[0], sB = sp[1];
  float cc[8] = {cA.x, cA.y, cA.z, cA.w, cB.x, cB.y, cB.z, cB.w};
  float ss[8] = {sA.x, sA.y, sA.z, sA.w, sB.x, sB.y, sB.z, sB.w};
  // q head hh<32 at col hh*128; k head (hh-32) at col 4096+(hh-32)*128 == hh*128
  u16* base = qkv + (size_t)bt * QSTR + hh * HDIM;
  bf16x8 v1 = *(const bf16x8*)(base + d0);
  bf16x8 v2 = *(const bf16x8*)(base + d0 + 64);
  bf16x8 o1, o2;
#pragma unroll
  for (int j = 0; j < 8; ++j) {
    float xa = (float)v1[j], xb = (float)v2[j];
    o1[j] = (__bf16)(xa * cc[j] - xb * ss[j]);
    o2[j] = (__bf16)(xb * cc[j] + xa * ss[j]);
  }
  *(bf16x8*)(base + d0) = o1;
  *(bf16x8*)(base + d0 + 64) = o2;
}

// ---------------- flash attention, QB=64 (4 waves x 16 rows), KVB=64 ----------------
__global__ __launch_bounds__(256) void attn_kernel(const u16* __restrict__ qp,
                                                   const u16* __restrict__ kp,
                                                   const u16* __restrict__ vtp,
                                                   u16* __restrict__ ctx) {
  __shared__ u16 Kt[64 * 128];
  __shared__ u16 Vt[128 * 64];
  __shared__ u16 Pl[4][16 * 64]; // per-wave P bounce, swizzled
  int tid = threadIdx.x;
  int w = tid >> 6, lane = tid & 63;
  int g = lane >> 4, li = lane & 15;
  int i0 = blockIdx.x * 64;
  int h = blockIdx.y, b = blockIdx.z;
  int kh = h >> 2; // repeat_interleave: q-head h -> kv-head h/4
  f32x4 zz = {0.f, 0.f, 0.f, 0.f};

  bf16x8 qf[4];
  size_t qrow = (size_t)(b * T_SEQ + i0 + w * 16 + li) * QSTR + h * HDIM;
#pragma unroll
  for (int c = 0; c < 4; ++c) qf[c] = *(const bf16x8*)(qp + qrow + c * 32 + g * 8);

  f32x4 o[8];
#pragma unroll
  for (int f = 0; f < 8; ++f) o[f] = zz;
  float m_s[4] = {-1e30f, -1e30f, -1e30f, -1e30f};
  float l_s[4] = {0.f, 0.f, 0.f, 0.f};

  int jmax = i0 + 63;
  for (int j0 = 0; j0 <= jmax; j0 += 64) {
    if (!((j0 < NGLOB) || (j0 + 63 > i0 - WINDOW))) continue; // fully-masked tile
    __syncthreads();
#pragma unroll
    for (int i = 0; i < 4; ++i) {
      int o8 = tid + 256 * i;
      int krow = o8 >> 4, kch = o8 & 15;
      size_t gk = (size_t)(b * T_SEQ + j0 + krow) * QSTR + kh * HDIM + kch * 8;
      *(bf16x8*)&Kt[(krow * 128 + kch * 8) ^ ((krow & 7) << 3)] = *(const bf16x8*)(kp + gk);
      int vrow = o8 >> 3, vch = o8 & 7; // vrow = hd
      size_t gv = ((size_t)(b * NKV + kh) * HDIM + vrow) * T_SEQ + j0 + vch * 8;
      *(bf16x8*)&Vt[(vrow * 64 + vch * 8) ^ ((vrow & 7) << 3)] = *(const bf16x8*)(vtp + gv);
    }
    __syncthreads();

    f32x4 s[4];
#pragma unroll
    for (int kb = 0; kb < 4; ++kb) s[kb] = zz;
#pragma unroll
    for (int c = 0; c < 4; ++c) {
      int hd0 = c * 32 + g * 8;
#pragma unroll
      for (int kb = 0; kb < 4; ++kb) {
        int key = kb * 16 + li;
        bf16x8 kf = *(const bf16x8*)&Kt[(key * 128 + hd0) ^ ((key & 7) << 3)];
        s[kb] = __builtin_amdgcn_mfma_f32_16x16x32_bf16(qf[c], kf, s[kb], 0, 0, 0);
      }
    }

    float corr[4];
#pragma unroll
    for (int r = 0; r < 4; ++r) {
      int irow = i0 + w * 16 + g * 4 + r;
      float x[4];
#pragma unroll
      for (int kb = 0; kb < 4; ++kb) {
        int j = j0 + kb * 16 + li;
        float xx = s[kb][r] * SCALE;
        bool vm = (j <= irow) && ((j > irow - WINDOW) || (j < NGLOB));
        x[kb] = vm ? xx : -1e30f;
      }
      float mt = fmaxf(fmaxf(x[0], x[1]), fmaxf(x[2], x[3]));
#pragma unroll
      for (int dd = 1; dd < 16; dd <<= 1) mt = fmaxf(mt, __shfl_xor(mt, dd, 64));
      float mn = fmaxf(m_s[r], mt);
      corr[r] = __expf(m_s[r] - mn);
      m_s[r] = mn;
      float rs = 0.f;
      int prow = g * 4 + r;
#pragma unroll
      for (int kb = 0; kb < 4; ++kb) {
        x[kb] = __expf(x[kb] - mn);
        rs += x[kb];
        Pl[w][(prow * 64 + kb * 16 + li) ^ ((prow & 7) << 3)] = f2b(x[kb]);
      }
#pragma unroll
      for (int dd = 1; dd < 16; dd <<= 1) rs += __shfl_xor(rs, dd, 64);
      l_s[r] = l_s[r] * corr[r] + rs;
    }
#pragma unroll
    for (int f = 0; f < 8; ++f) {
      o[f][0] *= corr[0]; o[f][1] *= corr[1];
      o[f][2] *= corr[2]; o[f][3] *= corr[3];
    }

    bf16x8 pa0 = *(const bf16x8*)&Pl[w][(li * 64 + 0 + g * 8) ^ ((li & 7) << 3)];
    bf16x8 pa1 = *(const bf16x8*)&Pl[w][(li * 64 + 32 + g * 8) ^ ((li & 7) << 3)];

#pragma unroll
    for (int f = 0; f < 8; ++f) {
      int hd = f * 16 + li;
      bf16x8 v0 = *(const bf16x8*)&Vt[(hd * 64 + 0 + g * 8) ^ ((li & 7) << 3)];
      bf16x8 v1 = *(const bf16x8*)&Vt[(hd * 64 + 32 + g * 8) ^ ((li & 7) << 3)];
      o[f] = __builtin_amdgcn_mfma_f32_16x16x32_bf16(pa0, v0, o[f], 0, 0, 0);
      o[f] = __builtin_amdgcn_mfma_f32_16x16x32_bf16(pa1, v1, o[f], 0, 0, 0);
    }
  }

#pragma unroll
  for (int f = 0; f < 8; ++f)
#pragma unroll
    for (int r = 0; r < 4; ++r) {
      size_t orow = (size_t)(b * T_SEQ + i0 + w * 16 + g * 4 + r) * (NH * HDIM) + h * HDIM + f * 16 + li;
      ctx[orow] = f2b(o[f][r] / l_s[r]);
    }
}

extern "C" void kernel_launch(void* const* d_in, const int* in_sizes, int n_in,
                              void* d_out, int out_size, void* d_ws, size_t ws_size,
                              hipStream_t stream) {
  const float* x    = (const float*)d_in[0];
  const float* Wq   = (const float*)d_in[1];
  const float* Wk   = (const float*)d_in[2];
  const float* Wv   = (const float*)d_in[3];
  const float* Wo   = (const float*)d_in[4];
  const float* cosp = (const float*)d_in[5];
  const float* sinp = (const float*)d_in[6];
  // d_in[7] = mask: recomputed analytically in-kernel.

  char* ws = (char*)d_ws;
  // ws layout (160 MiB total); aliasing is stream-ordered:
  //   ctx aliases xb (dead after QKV GEMM); vT aliases Wqkvt (dead after QKV GEMM)
  u16* xb     = (u16*)(ws + 0ull);           // 32 MiB [4096,4096]
  u16* Wqkvt  = (u16*)(ws + 33554432ull);    // 48 MiB [6144,4096]
  u16* Wot    = (u16*)(ws + 83886080ull);    // 32 MiB [4096,4096]
  u16* qkv    = (u16*)(ws + 117440512ull);   // 48 MiB [4096,6144]
  u16* ctx    = xb;
  u16* vT     = Wqkvt;                        // 8 MiB [B][KH*HD][T]

  convert_bf16_kernel<<<16384, 256, 0, stream>>>(x, xb, 4194304);
  transpose_w_kernel<<<dim3(128, 128), 256, 0, stream>>>(Wq, Wqkvt, 4096, 4096);
  transpose_w_kernel<<<dim3(32, 128), 256, 0, stream>>>(Wk, Wqkvt + (size_t)4096 * 4096, 4096, 1024);
  transpose_w_kernel<<<dim3(32, 128), 256, 0, stream>>>(Wv, Wqkvt + (size_t)5120 * 4096, 4096, 1024);
  transpose_w_kernel<<<dim3(128, 128), 256, 0, stream>>>(Wo, Wot, 4096, 4096);

  // fused QKV projection: [4096,4096] @ [6144,4096]^T -> [4096,6144]
  // grid 32x16 = 512 blocks = exactly 2 full machine rounds (packing fix)
  gemm192_kernel<<<dim3(32, 16), 512, 0, stream>>>(xb, Wqkvt, qkv, QSTR, 4096);

  transpose_v_kernel<<<dim3(32, 64, 2), 256, 0, stream>>>(qkv + 5120, vT);

  rope_kernel<<<5120, 256, 0, stream>>>(qkv, cosp, sinp);

  attn_kernel<<<dim3(32, 32, 2), 256, 0, stream>>>(qkv, qkv + 4096, vT, ctx);

  gemm256_kernel<float><<<dim3(16, 16), 512, 0, stream>>>(ctx, Wot, (float*)d_out, 4096, 4096);
}

// Round 6
// 553.418 us; speedup vs baseline: 1.7138x; 1.0434x over previous
//
#include <hip/hip_runtime.h>
#include <stdint.h>

typedef unsigned short u16;
typedef __bf16 bf16x8 __attribute__((ext_vector_type(8)));
typedef float f32x4 __attribute__((ext_vector_type(4)));

#define D_MODEL 4096
#define T_SEQ   2048
#define B_SZ    2
#define NH      32
#define NKV     8
#define HDIM    128
#define WINDOW  1024
#define NGLOB   32
#define QSTR    6144   // fused qkv row stride: [q 4096 | k 1024 | v 1024]

static constexpr float SCALE = 0.08838834764831845f; // 1/sqrt(128)

__device__ __forceinline__ u16 f2b(float f) {
  __bf16 h = (__bf16)f;
  return __builtin_bit_cast(u16, h);
}

// ---------------- x f32 -> bf16 (vectorized) ----------------
__global__ __launch_bounds__(256) void convert_bf16_kernel(const float* __restrict__ in,
                                                           u16* __restrict__ outp, int n4) {
  int i = blockIdx.x * 256 + threadIdx.x;
  if (i >= n4) return;
  float4 v = ((const float4*)in)[i];
  ushort4 o;
  o.x = f2b(v.x); o.y = f2b(v.y); o.z = f2b(v.z); o.w = f2b(v.w);
  ((ushort4*)outp)[i] = o;
}

// ---------------- W [K,N] f32 -> Wt [N,K] bf16 ----------------
__global__ __launch_bounds__(256) void transpose_w_kernel(const float* __restrict__ W,
                                                          u16* __restrict__ Wt, int Kd, int Nd) {
  __shared__ float tile[32][33];
  int tx = threadIdx.x & 31, ty = threadIdx.x >> 5;
  int bx = blockIdx.x * 32; // N
  int by = blockIdx.y * 32; // K
#pragma unroll
  for (int i = 0; i < 4; ++i)
    tile[ty + i * 8][tx] = W[(size_t)(by + ty + i * 8) * Nd + bx + tx];
  __syncthreads();
#pragma unroll
  for (int i = 0; i < 4; ++i)
    Wt[(size_t)(bx + ty + i * 8) * Kd + by + tx] = f2b(tile[tx][ty + i * 8]);
}

// ---------------- v slice of qkv -> vT [B][KH*HD][T] bf16 ----------------
__global__ __launch_bounds__(256) void transpose_v_kernel(const u16* __restrict__ in,
                                                          u16* __restrict__ outp) {
  __shared__ u16 tile[32][33];
  int tx = threadIdx.x & 31, ty = threadIdx.x >> 5;
  int x0 = blockIdx.x * 32; // hd' = kh*128+hd (0..1023)
  int t0 = blockIdx.y * 32; // t
  int b = blockIdx.z;
  const u16* src = in + (size_t)b * T_SEQ * QSTR;
  u16* dst = outp + (size_t)b * (NKV * HDIM) * T_SEQ;
#pragma unroll
  for (int i = 0; i < 4; ++i)
    tile[ty + i * 8][tx] = src[(size_t)(t0 + ty + i * 8) * QSTR + x0 + tx];
  __syncthreads();
#pragma unroll
  for (int i = 0; i < 4; ++i)
    dst[(size_t)(x0 + ty + i * 8) * T_SEQ + t0 + tx] = tile[tx][ty + i * 8];
}

// ---------------- 256x256 8-phase bf16 GEMM (proven): C = A @ Bt^T ----------------
template <typename CT>
__global__ __launch_bounds__(512, 2) void gemm256_kernel(const u16* __restrict__ A,
                                                         const u16* __restrict__ Bt,
                                                         CT* __restrict__ C,
                                                         int ldc, int K) {
  __shared__ u16 sh[65536]; // [buf:2][A 16384 | B 16384] u16 = 128 KiB
  const int tid = threadIdx.x;
  const int wave = tid >> 6, lane = tid & 63;
  const int g = lane >> 4, li = lane & 15;
  const int wr = wave >> 2, wc = wave & 3;
  const int m0 = blockIdx.y * 256, n0 = blockIdx.x * 256;
  const int r0 = tid >> 3;
  const int cs = ((tid & 7) ^ ((tid >> 3) & 7)) << 3;
  const u16* pA = A + (size_t)(m0 + r0) * K + cs;
  const u16* pB = Bt + (size_t)(n0 + r0) * K + cs;
  const int sl0 = (g ^ (li & 7)) << 3;
  const int sl1 = ((4 + g) ^ (li & 7)) << 3;
  const int nT = K >> 6;

  f32x4 acc[8][4];
  f32x4 zz = {0.f, 0.f, 0.f, 0.f};
#pragma unroll
  for (int M = 0; M < 8; ++M)
#pragma unroll
    for (int n = 0; n < 4; ++n) acc[M][n] = zz;

  auto stage = [&](const u16* src0, int ts, int dstBase) {
#pragma unroll
    for (int i = 0; i < 2; ++i) {
      const u16* s = src0 + (size_t)(i * 64) * K + ts * 64;
      __builtin_amdgcn_global_load_lds((__attribute__((address_space(1))) void*)s,
                                       (__attribute__((address_space(3))) void*)(sh + dstBase + i * 4096 + wave * 512),
                                       16, 0, 0);
    }
  };

  stage(pA, 0, 0);
  stage(pA + (size_t)128 * K, 0, 8192);
  stage(pB, 0, 16384);
  stage(pB + (size_t)128 * K, 0, 24576);
  stage(pB, 1, 32768 + 16384);
  stage(pB + (size_t)128 * K, 1, 32768 + 24576);
  stage(pA, 1, 32768);
  asm volatile("s_waitcnt vmcnt(6)" ::: "memory");
  __builtin_amdgcn_s_barrier();

  bf16x8 afr[4][2], bfr[4][2];
  for (int t = 0; t < nT; ++t) {
    const int cur = t & 1;
    const int ab = cur * 32768, bb = ab + 16384;
    const int nb = (cur ^ 1) * 32768;
    const int tn1 = (t + 1 < nT) ? t + 1 : nT - 1;
    const int tn2 = (t + 2 < nT) ? t + 2 : nT - 1;
#pragma unroll
    for (int n = 0; n < 4; ++n) {
      int row = wc * 64 + n * 16 + li;
      bfr[n][0] = *(const bf16x8*)&sh[bb + row * 64 + sl0];
      bfr[n][1] = *(const bf16x8*)&sh[bb + row * 64 + sl1];
    }
#pragma unroll
    for (int m = 0; m < 4; ++m) {
      int row = wr * 128 + m * 16 + li;
      afr[m][0] = *(const bf16x8*)&sh[ab + row * 64 + sl0];
      afr[m][1] = *(const bf16x8*)&sh[ab + row * 64 + sl1];
    }
    stage(pA + (size_t)128 * K, tn1, nb + 8192);
    __builtin_amdgcn_s_barrier();
    asm volatile("s_waitcnt lgkmcnt(0)" ::: "memory");
    __builtin_amdgcn_sched_barrier(0);
    __builtin_amdgcn_s_setprio(1);
#pragma unroll
    for (int m = 0; m < 4; ++m)
#pragma unroll
      for (int n = 0; n < 2; ++n) {
        acc[m][n] = __builtin_amdgcn_mfma_f32_16x16x32_bf16(afr[m][0], bfr[n][0], acc[m][n], 0, 0, 0);
        acc[m][n] = __builtin_amdgcn_mfma_f32_16x16x32_bf16(afr[m][1], bfr[n][1], acc[m][n], 0, 0, 0);
      }
    __builtin_amdgcn_s_setprio(0);
    __builtin_amdgcn_s_barrier();
    stage(pB, tn2, bb);
    __builtin_amdgcn_s_barrier();
    __builtin_amdgcn_s_setprio(1);
#pragma unroll
    for (int m = 0; m < 4; ++m)
#pragma unroll
      for (int n = 2; n < 4; ++n) {
        acc[m][n] = __builtin_amdgcn_mfma_f32_16x16x32_bf16(afr[m][0], bfr[n][0], acc[m][n], 0, 0, 0);
        acc[m][n] = __builtin_amdgcn_mfma_f32_16x16x32_bf16(afr[m][1], bfr[n][1], acc[m][n], 0, 0, 0);
      }
    __builtin_amdgcn_s_setprio(0);
    __builtin_amdgcn_s_barrier();
#pragma unroll
    for (int m = 0; m < 4; ++m) {
      int row = wr * 128 + 64 + m * 16 + li;
      afr[m][0] = *(const bf16x8*)&sh[ab + row * 64 + sl0];
      afr[m][1] = *(const bf16x8*)&sh[ab + row * 64 + sl1];
    }
    stage(pB + (size_t)128 * K, tn2, bb + 8192);
    __builtin_amdgcn_s_barrier();
    asm volatile("s_waitcnt lgkmcnt(0)" ::: "memory");
    __builtin_amdgcn_sched_barrier(0);
    __builtin_amdgcn_s_setprio(1);
#pragma unroll
    for (int m = 0; m < 4; ++m)
#pragma unroll
      for (int n = 0; n < 2; ++n) {
        acc[4 + m][n] = __builtin_amdgcn_mfma_f32_16x16x32_bf16(afr[m][0], bfr[n][0], acc[4 + m][n], 0, 0, 0);
        acc[4 + m][n] = __builtin_amdgcn_mfma_f32_16x16x32_bf16(afr[m][1], bfr[n][1], acc[4 + m][n], 0, 0, 0);
      }
    __builtin_amdgcn_s_setprio(0);
    __builtin_amdgcn_s_barrier();
    stage(pA, tn2, ab);
    __builtin_amdgcn_s_barrier();
    __builtin_amdgcn_s_setprio(1);
#pragma unroll
    for (int m = 0; m < 4; ++m)
#pragma unroll
      for (int n = 2; n < 4; ++n) {
        acc[4 + m][n] = __builtin_amdgcn_mfma_f32_16x16x32_bf16(afr[m][0], bfr[n][0], acc[4 + m][n], 0, 0, 0);
        acc[4 + m][n] = __builtin_amdgcn_mfma_f32_16x16x32_bf16(afr[m][1], bfr[n][1], acc[4 + m][n], 0, 0, 0);
      }
    __builtin_amdgcn_s_setprio(0);
    asm volatile("s_waitcnt vmcnt(6)" ::: "memory");
    __builtin_amdgcn_s_barrier();
  }
#pragma unroll
  for (int M = 0; M < 8; ++M)
#pragma unroll
    for (int n = 0; n < 4; ++n)
#pragma unroll
      for (int r = 0; r < 4; ++r) {
        int row = m0 + wr * 128 + M * 16 + g * 4 + r;
        int col = n0 + wc * 64 + n * 16 + li;
        if constexpr (sizeof(CT) == 2)
          C[(size_t)row * ldc + col] = (CT)f2b(acc[M][n][r]);
        else
          C[(size_t)row * ldc + col] = acc[M][n][r];
      }
}

// ---------------- 256x192 4-phase bf16 GEMM: packs N=6144 into 512 blocks ----------------
__global__ __launch_bounds__(512, 2) void gemm192_kernel(const u16* __restrict__ A,
                                                         const u16* __restrict__ Bt,
                                                         u16* __restrict__ C,
                                                         int ldc, int K) {
  __shared__ u16 sh[57344]; // dbuf x [A 16384 | B 12288] u16 = 112 KiB
  const int tid = threadIdx.x;
  const int wave = tid >> 6, lane = tid & 63;
  const int g = lane >> 4, li = lane & 15;
  const int wr = wave >> 2, wc = wave & 3;
  const int m0 = blockIdx.y * 256, n0 = blockIdx.x * 192;
  const int r0 = tid >> 3;
  const int cs = ((tid & 7) ^ ((tid >> 3) & 7)) << 3;
  const u16* pA = A + (size_t)(m0 + r0) * K + cs;
  const u16* pB = Bt + (size_t)(n0 + r0) * K + cs;
  const int sl0 = (g ^ (li & 7)) << 3;
  const int sl1 = ((4 + g) ^ (li & 7)) << 3;
  const int nT = K >> 6;

  f32x4 acc[8][3];
  f32x4 zz = {0.f, 0.f, 0.f, 0.f};
#pragma unroll
  for (int M = 0; M < 8; ++M)
#pragma unroll
    for (int n = 0; n < 3; ++n) acc[M][n] = zz;

  auto stage64 = [&](const u16* src0, int ts, int dstU16) {
    __builtin_amdgcn_global_load_lds(
        (__attribute__((address_space(1))) void*)(src0 + (size_t)ts * 64),
        (__attribute__((address_space(3))) void*)(sh + dstU16 + wave * 512), 16, 0, 0);
  };

#pragma unroll
  for (int u = 0; u < 4; ++u) stage64(pA + (size_t)(u * 64) * K, 0, u * 4096);
#pragma unroll
  for (int u = 0; u < 3; ++u) stage64(pB + (size_t)(u * 64) * K, 0, 16384 + u * 4096);
#pragma unroll
  for (int u = 0; u < 4; ++u) stage64(pA + (size_t)(u * 64) * K, 1, 28672 + u * 4096);
#pragma unroll
  for (int u = 0; u < 3; ++u) stage64(pB + (size_t)(u * 64) * K, 1, 28672 + 16384 + u * 4096);
  asm volatile("s_waitcnt vmcnt(7)" ::: "memory");
  __builtin_amdgcn_s_barrier();

  bf16x8 afr[4][2], bfr[3][2];
  for (int t = 0; t < nT; ++t) {
    const int ab = (t & 1) * 28672, bb = ab + 16384;
    const int tn2 = (t + 2 < nT) ? t + 2 : nT - 1;
#pragma unroll
    for (int n = 0; n < 3; ++n) {
      int row = wc * 48 + n * 16 + li;
      bfr[n][0] = *(const bf16x8*)&sh[bb + row * 64 + sl0];
      bfr[n][1] = *(const bf16x8*)&sh[bb + row * 64 + sl1];
    }
#pragma unroll
    for (int m = 0; m < 4; ++m) {
      int row = wr * 128 + m * 16 + li;
      afr[m][0] = *(const bf16x8*)&sh[ab + row * 64 + sl0];
      afr[m][1] = *(const bf16x8*)&sh[ab + row * 64 + sl1];
    }
    __builtin_amdgcn_s_barrier();
    asm volatile("s_waitcnt lgkmcnt(0)" ::: "memory");
    __builtin_amdgcn_sched_barrier(0);
    __builtin_amdgcn_s_setprio(1);
#pragma unroll
    for (int m = 0; m < 4; ++m)
#pragma unroll
      for (int n = 0; n < 2; ++n) {
        acc[m][n] = __builtin_amdgcn_mfma_f32_16x16x32_bf16(afr[m][0], bfr[n][0], acc[m][n], 0, 0, 0);
        acc[m][n] = __builtin_amdgcn_mfma_f32_16x16x32_bf16(afr[m][1], bfr[n][1], acc[m][n], 0, 0, 0);
      }
    __builtin_amdgcn_s_setprio(0);
    __builtin_amdgcn_s_barrier();
    stage64(pB, tn2, bb);
    stage64(pB + (size_t)64 * K, tn2, bb + 4096);
    stage64(pA, tn2, ab);
    __builtin_amdgcn_s_barrier();
    __builtin_amdgcn_s_setprio(1);
#pragma unroll
    for (int m = 0; m < 4; ++m) {
      acc[m][2] = __builtin_amdgcn_mfma_f32_16x16x32_bf16(afr[m][0], bfr[2][0], acc[m][2], 0, 0, 0);
      acc[m][2] = __builtin_amdgcn_mfma_f32_16x16x32_bf16(afr[m][1], bfr[2][1], acc[m][2], 0, 0, 0);
    }
    __builtin_amdgcn_s_setprio(0);
    __builtin_amdgcn_s_barrier();
#pragma unroll
    for (int m = 0; m < 4; ++m) {
      int row = wr * 128 + 64 + m * 16 + li;
      afr[m][0] = *(const bf16x8*)&sh[ab + row * 64 + sl0];
      afr[m][1] = *(const bf16x8*)&sh[ab + row * 64 + sl1];
    }
    stage64(pB + (size_t)128 * K, tn2, bb + 8192);
    stage64(pA + (size_t)128 * K, tn2, ab + 8192);
    __builtin_amdgcn_s_barrier();
    asm volatile("s_waitcnt lgkmcnt(0)" ::: "memory");
    __builtin_amdgcn_sched_barrier(0);
    __builtin_amdgcn_s_setprio(1);
#pragma unroll
    for (int m = 0; m < 4; ++m)
#pragma unroll
      for (int n = 0; n < 2; ++n) {
        acc[4 + m][n] = __builtin_amdgcn_mfma_f32_16x16x32_bf16(afr[m][0], bfr[n][0], acc[4 + m][n], 0, 0, 0);
        acc[4 + m][n] = __builtin_amdgcn_mfma_f32_16x16x32_bf16(afr[m][1], bfr[n][1], acc[4 + m][n], 0, 0, 0);
      }
    __builtin_amdgcn_s_setprio(0);
    __builtin_amdgcn_s_barrier();
    stage64(pA + (size_t)64 * K, tn2, ab + 4096);
    stage64(pA + (size_t)192 * K, tn2, ab + 12288);
    __builtin_amdgcn_s_barrier();
    __builtin_amdgcn_s_setprio(1);
#pragma unroll
    for (int m = 0; m < 4; ++m) {
      acc[4 + m][2] = __builtin_amdgcn_mfma_f32_16x16x32_bf16(afr[m][0], bfr[2][0], acc[4 + m][2], 0, 0, 0);
      acc[4 + m][2] = __builtin_amdgcn_mfma_f32_16x16x32_bf16(afr[m][1], bfr[2][1], acc[4 + m][2], 0, 0, 0);
    }
    __builtin_amdgcn_s_setprio(0);
    asm volatile("s_waitcnt vmcnt(7)" ::: "memory");
    __builtin_amdgcn_s_barrier();
  }
#pragma unroll
  for (int M = 0; M < 8; ++M)
#pragma unroll
    for (int n = 0; n < 3; ++n)
#pragma unroll
      for (int r = 0; r < 4; ++r) {
        int row = m0 + wr * 128 + M * 16 + g * 4 + r;
        int col = n0 + wc * 48 + n * 16 + li;
        C[(size_t)row * ldc + col] = f2b(acc[M][n][r]);
      }
}

// ---------------- RoPE in place on fused qkv, bf16x8-vectorized ----------------
// Folds the attention scale 1/sqrt(HD) into the q heads (f32, single rounding).
__global__ __launch_bounds__(256) void rope_kernel(u16* __restrict__ qkv,
                                                   const float* __restrict__ cosp,
                                                   const float* __restrict__ sinp) {
  int idx = blockIdx.x * 256 + threadIdx.x; // B*T*(NH+NKV)*8
  int d8 = idx & 7;
  int rest = idx >> 3;
  int hh = rest % (NH + NKV);
  int bt = rest / (NH + NKV);
  if (bt >= B_SZ * T_SEQ) return;
  int tok = bt & (T_SEQ - 1);
  int d0 = d8 * 8;
  const float4* cp = (const float4*)(cosp + (size_t)tok * HDIM + d0);
  const float4* sp = (const float4*)(sinp + (size_t)tok * HDIM + d0);
  float4 cA = cp[0], cB = cp[1];
  float4 sA = sp[0], sB = sp[1];
  float cc[8] = {cA.x, cA.y, cA.z, cA.w, cB.x, cB.y, cB.z, cB.w};
  float ss[8] = {sA.x, sA.y, sA.z, sA.w, sB.x, sB.y, sB.z, sB.w};
  float scl = (hh < NH) ? SCALE : 1.0f;
  u16* base = qkv + (size_t)bt * QSTR + hh * HDIM;
  bf16x8 v1 = *(const bf16x8*)(base + d0);
  bf16x8 v2 = *(const bf16x8*)(base + d0 + 64);
  bf16x8 o1, o2;
#pragma unroll
  for (int j = 0; j < 8; ++j) {
    float xa = (float)v1[j], xb = (float)v2[j];
    o1[j] = (__bf16)((xa * cc[j] - xb * ss[j]) * scl);
    o2[j] = (__bf16)((xb * cc[j] + xa * ss[j]) * scl);
  }
  *(bf16x8*)(base + d0) = o1;
  *(bf16x8*)(base + d0 + 64) = o2;
}

// ---------------- flash attention, QB=128 (8 waves x 16 rows), KVB=64 ----------------
// Swapped QK^T (mfma(K,Q) -> S^T): each lane owns q-row li -> softmax is lane-local
// + 2 shfl_xor. K/V staged via global_load_lds with pre-swizzled global source.
__global__ __launch_bounds__(512) void attn_kernel(const u16* __restrict__ qp,
                                                   const u16* __restrict__ kp,
                                                   const u16* __restrict__ vtp,
                                                   u16* __restrict__ ctx) {
  __shared__ u16 Kt[64 * 128];   // row-major, XOR-swizzled
  __shared__ u16 Vt[128 * 64];   // hd-major, XOR-swizzled
  __shared__ u16 Pl[8][16 * 64]; // per-wave P bounce, swizzled
  int tid = threadIdx.x;
  int w = tid >> 6, lane = tid & 63;
  int g = lane >> 4, li = lane & 15;
  int i0 = blockIdx.x * 128;
  int h = blockIdx.y, b = blockIdx.z;
  int kh = h >> 2; // repeat_interleave: q-head h -> kv-head h/4
  f32x4 zz = {0.f, 0.f, 0.f, 0.f};

  // Q fragments (B-operand; col=li=q, k=c*32+g*8+e); q pre-scaled by 1/sqrt(HD)
  bf16x8 qf[4];
  size_t qrow = (size_t)(b * T_SEQ + i0 + w * 16 + li) * QSTR + h * HDIM;
#pragma unroll
  for (int c = 0; c < 4; ++c) qf[c] = *(const bf16x8*)(qp + qrow + c * 32 + g * 8);

  f32x4 o[8];
#pragma unroll
  for (int f = 0; f < 8; ++f) o[f] = zz;
  float m_s = -1e30f, l_s = 0.f; // per-lane stats for q = i0 + w*16 + li
  const int irow = i0 + w * 16 + li;

  int jmax = i0 + 127;
  for (int j0 = 0; j0 <= jmax; j0 += 64) {
    // Tile needed iff it intersects union over rows [i0, i0+127] of
    // global [0,NGLOB) or window (irow-WINDOW, irow]: union lower bound
    // comes from the LOWEST row i0 (R5 bug: used i0+127 -> dropped keys).
    if (!((j0 < NGLOB) || (j0 + 63 > i0 - WINDOW))) continue;
    __syncthreads();
    // stage K [64][128] + V^T [128][64] via global_load_lds; swizzle on the SOURCE
#pragma unroll
    for (int i = 0; i < 2; ++i) {
      int o8 = tid + 512 * i;
      int krow = o8 >> 4, kch = o8 & 15;
      size_t gk = (size_t)(b * T_SEQ + j0 + krow) * QSTR + kh * HDIM + (kch ^ (krow & 7)) * 8;
      __builtin_amdgcn_global_load_lds((__attribute__((address_space(1))) void*)(kp + gk),
                                       (__attribute__((address_space(3))) void*)(Kt + o8 * 8),
                                       16, 0, 0);
      int vrow = o8 >> 3, vch = o8 & 7;
      size_t gv = ((size_t)(b * NKV + kh) * HDIM + vrow) * T_SEQ + j0 + (vch ^ (vrow & 7)) * 8;
      __builtin_amdgcn_global_load_lds((__attribute__((address_space(1))) void*)(vtp + gv),
                                       (__attribute__((address_space(3))) void*)(Vt + o8 * 8),
                                       16, 0, 0);
    }
    __syncthreads();

    // S^T = K @ Q^T : rows=keys (kb*16+g*4+r), cols=q (li)
    f32x4 s[4];
#pragma unroll
    for (int kb = 0; kb < 4; ++kb) s[kb] = zz;
#pragma unroll
    for (int c = 0; c < 4; ++c) {
      int hd0 = c * 32 + g * 8;
#pragma unroll
      for (int kb = 0; kb < 4; ++kb) {
        int key = kb * 16 + li;
        bf16x8 kf = *(const bf16x8*)&Kt[(key * 128 + hd0) ^ ((key & 7) << 3)];
        s[kb] = __builtin_amdgcn_mfma_f32_16x16x32_bf16(kf, qf[c], s[kb], 0, 0, 0);
      }
    }

    // mask + online softmax: lane-local (q=li), all 16 rows in parallel
    float x[4][4];
    float mt = -1e30f;
#pragma unroll
    for (int kb = 0; kb < 4; ++kb)
#pragma unroll
      for (int r = 0; r < 4; ++r) {
        int j = j0 + kb * 16 + g * 4 + r;
        bool vm = (j <= irow) && ((j > irow - WINDOW) || (j < NGLOB));
        float xx = vm ? s[kb][r] : -1e30f;
        x[kb][r] = xx;
        mt = fmaxf(mt, xx);
      }
    mt = fmaxf(mt, __shfl_xor(mt, 16, 64));
    mt = fmaxf(mt, __shfl_xor(mt, 32, 64));
    float mn = fmaxf(m_s, mt);
    float corr = __expf(m_s - mn);
    m_s = mn;
    float rs = 0.f;
#pragma unroll
    for (int kb = 0; kb < 4; ++kb) {
      ushort4 pk;
#pragma unroll
      for (int r = 0; r < 4; ++r) {
        float p = __expf(x[kb][r] - mn);
        rs += p;
        ((u16*)&pk)[r] = f2b(p);
      }
      *(ushort4*)&Pl[w][(li * 64 + kb * 16 + g * 4) ^ ((li & 7) << 3)] = pk;
    }
    rs += __shfl_xor(rs, 16, 64);
    rs += __shfl_xor(rs, 32, 64);
    l_s = l_s * corr + rs;

    // redistribute corr to O-row owners (O row q = g*4+r, stats at lane li'=g*4+r)
    float c4[4];
#pragma unroll
    for (int r = 0; r < 4; ++r) c4[r] = __shfl(corr, g * 4 + r, 16);
#pragma unroll
    for (int f = 0; f < 8; ++f) {
      o[f][0] *= c4[0]; o[f][1] *= c4[1];
      o[f][2] *= c4[2]; o[f][3] *= c4[3];
    }

    // P A-frags (row=li=q): two k-chunks of 32
    bf16x8 pa0 = *(const bf16x8*)&Pl[w][(li * 64 + 0 + g * 8) ^ ((li & 7) << 3)];
    bf16x8 pa1 = *(const bf16x8*)&Pl[w][(li * 64 + 32 + g * 8) ^ ((li & 7) << 3)];

    // O += P @ V : B-frags are vector reads from hd-major Vt
#pragma unroll
    for (int f = 0; f < 8; ++f) {
      int hd = f * 16 + li;
      bf16x8 v0 = *(const bf16x8*)&Vt[(hd * 64 + 0 + g * 8) ^ ((li & 7) << 3)];
      bf16x8 v1 = *(const bf16x8*)&Vt[(hd * 64 + 32 + g * 8) ^ ((li & 7) << 3)];
      o[f] = __builtin_amdgcn_mfma_f32_16x16x32_bf16(pa0, v0, o[f], 0, 0, 0);
      o[f] = __builtin_amdgcn_mfma_f32_16x16x32_bf16(pa1, v1, o[f], 0, 0, 0);
    }
  }

  // epilogue: O rows q=g*4+r need l from lane li'=g*4+r
  float l4[4];
#pragma unroll
  for (int r = 0; r < 4; ++r) l4[r] = __shfl(l_s, g * 4 + r, 16);
#pragma unroll
  for (int f = 0; f < 8; ++f)
#pragma unroll
    for (int r = 0; r < 4; ++r) {
      size_t orow = (size_t)(b * T_SEQ + i0 + w * 16 + g * 4 + r) * (NH * HDIM) + h * HDIM + f * 16 + li;
      ctx[orow] = f2b(o[f][r] / l4[r]);
    }
}

extern "C" void kernel_launch(void* const* d_in, const int* in_sizes, int n_in,
                              void* d_out, int out_size, void* d_ws, size_t ws_size,
                              hipStream_t stream) {
  const float* x    = (const float*)d_in[0];
  const float* Wq   = (const float*)d_in[1];
  const float* Wk   = (const float*)d_in[2];
  const float* Wv   = (const float*)d_in[3];
  const float* Wo   = (const float*)d_in[4];
  const float* cosp = (const float*)d_in[5];
  const float* sinp = (const float*)d_in[6];
  // d_in[7] = mask: recomputed analytically in-kernel.

  char* ws = (char*)d_ws;
  u16* xb     = (u16*)(ws + 0ull);           // 32 MiB [4096,4096]
  u16* Wqkvt  = (u16*)(ws + 33554432ull);    // 48 MiB [6144,4096]
  u16* Wot    = (u16*)(ws + 83886080ull);    // 32 MiB [4096,4096]
  u16* qkv    = (u16*)(ws + 117440512ull);   // 48 MiB [4096,6144]
  u16* ctx    = xb;
  u16* vT     = Wqkvt;                        // 8 MiB [B][KH*HD][T]

  convert_bf16_kernel<<<16384, 256, 0, stream>>>(x, xb, 4194304);
  transpose_w_kernel<<<dim3(128, 128), 256, 0, stream>>>(Wq, Wqkvt, 4096, 4096);
  transpose_w_kernel<<<dim3(32, 128), 256, 0, stream>>>(Wk, Wqkvt + (size_t)4096 * 4096, 4096, 1024);
  transpose_w_kernel<<<dim3(32, 128), 256, 0, stream>>>(Wv, Wqkvt + (size_t)5120 * 4096, 4096, 1024);
  transpose_w_kernel<<<dim3(128, 128), 256, 0, stream>>>(Wo, Wot, 4096, 4096);

  gemm192_kernel<<<dim3(32, 16), 512, 0, stream>>>(xb, Wqkvt, qkv, QSTR, 4096);

  transpose_v_kernel<<<dim3(32, 64, 2), 256, 0, stream>>>(qkv + 5120, vT);

  rope_kernel<<<5120, 256, 0, stream>>>(qkv, cosp, sinp);

  attn_kernel<<<dim3(16, 32, 2), 512, 0, stream>>>(qkv, qkv + 4096, vT, ctx);

  gemm256_kernel<float><<<dim3(16, 16), 512, 0, stream>>>(ctx, Wot, (float*)d_out, 4096, 4096);
}